// Round 6
// baseline (449.981 us; speedup 1.0000x reference)
//
#include <hip/hip_runtime.h>
#include <hip/hip_bf16.h>
#include <math.h>

// ---------------------------------------------------------------------------
// DeepseekV2 MoE: T=16384 tokens, H=1024, E=8 routed (top-2) + 1 shared, I=512
// Round 10:
//  - yb packed float4 fragment layout: yb4[(row*16+nseg)*16+l16] = lane's 4
//    cols (nseg*64 + in*16 + l16). Write (k_down_rs) and read (k_down_sc) use
//    the same tile/lane mapping -> 16B/lane coalesced both ways (was 4x4B
//    strided). fp32 kept: no precision change.
//  - Launch fusion: 3 transposes + scan -> 1 kernel (z in [0,27), scan folded
//    into block (0,0,26)). 9 launches -> 7.
//  - k_gu routed split into two z-halves (~54us each) so the rocprof top-5
//    finally surfaces the second-tier dispatches (rs/sc/gate visibility).
//  - Atomic fallback retained behind ws_size check.
// ---------------------------------------------------------------------------

#define T_TOTAL 16384
#define HDIM 1024
#define IDIM 512
#define NE 9  // 8 routed + 1 shared (expert index 8)
#define CNT_STRIDE 16
#define SH_BASE 32768  // packed-inter row where shared expert starts

typedef __bf16 bf16x8 __attribute__((ext_vector_type(8)));
typedef float f32x4 __attribute__((ext_vector_type(4)));

typedef __attribute__((address_space(1))) void gvoid_t;
typedef __attribute__((address_space(3))) void lvoid_t;

__device__ __forceinline__ void load_lds16(const void* g, void* l) {
  // 16B/lane; LDS dest = wave-uniform base + lane*16 (global src may scatter)
  __builtin_amdgcn_global_load_lds((const gvoid_t*)g, (lvoid_t*)l, 16, 0, 0);
}

__device__ __forceinline__ f32x4 mfma_bf16(bf16x8 a, bf16x8 b, f32x4 c) {
  return __builtin_amdgcn_mfma_f32_16x16x32_bf16(a, b, c, 0, 0, 0);
}

// ---------------------------------------------------------------------------
// Gate: block-aggregated slot assignment. Also writes inv[t*2+j] = e*16384+slot
// (T_TOTAL = 2^14 -> decode e = v>>14, slot = v&16383).
// ---------------------------------------------------------------------------
__global__ __launch_bounds__(256) void k_gate(const float* __restrict__ x,
                                              const float* __restrict__ gw,
                                              __bf16* __restrict__ xb,
                                              int* __restrict__ tok,
                                              float* __restrict__ wtl,
                                              int* __restrict__ cnt,
                                              int* __restrict__ inv) {
  __shared__ int s_eid[64][2];
  __shared__ float s_wt[64][2];
  __shared__ int s_rank[64][2];
  __shared__ int lcnt[8];
  __shared__ int lbase[8];
  const int wv = threadIdx.x >> 6, lane = threadIdx.x & 63;
  if (threadIdx.x < 8) lcnt[threadIdx.x] = 0;
  __syncthreads();

  for (int i = 0; i < 16; i++) {
    const int tl = wv * 16 + i;
    const int t = blockIdx.x * 64 + tl;
    const float* xr = x + (size_t)t * HDIM + lane * 16;
    float4 xv[4];
#pragma unroll
    for (int j = 0; j < 4; j++) xv[j] = ((const float4*)xr)[j];

    bf16x8 v0, v1;
#pragma unroll
    for (int j = 0; j < 8; j++) v0[j] = (__bf16)((const float*)xv)[j];
#pragma unroll
    for (int j = 0; j < 8; j++) v1[j] = (__bf16)((const float*)xv)[j + 8];
    bf16x8* xbo = (bf16x8*)(xb + (size_t)t * HDIM + lane * 16);
    xbo[0] = v0;
    xbo[1] = v1;

    float acc[8];
#pragma unroll
    for (int e = 0; e < 8; e++) {
      const float4* gp = (const float4*)(gw + e * HDIM + lane * 16);
      float s = 0.f;
#pragma unroll
      for (int j = 0; j < 4; j++) {
        float4 g = gp[j];
        s += xv[j].x * g.x + xv[j].y * g.y + xv[j].z * g.z + xv[j].w * g.w;
      }
      acc[e] = s;
    }
#pragma unroll
    for (int d = 32; d >= 1; d >>= 1) {
#pragma unroll
      for (int e = 0; e < 8; e++) acc[e] += __shfl_xor(acc[e], d, 64);
    }
    if (lane == 0) {
      float mx = acc[0];
#pragma unroll
      for (int e = 1; e < 8; e++) mx = fmaxf(mx, acc[e]);
      float p[8], Z = 0.f;
#pragma unroll
      for (int e = 0; e < 8; e++) {
        p[e] = expf(acc[e] - mx);
        Z += p[e];
      }
#pragma unroll
      for (int e = 0; e < 8; e++) p[e] /= Z;
      int i1 = 0;
#pragma unroll
      for (int e = 1; e < 8; e++)
        if (p[e] > p[i1]) i1 = e;
      int i2 = (i1 == 0) ? 1 : 0;
#pragma unroll
      for (int e = 0; e < 8; e++)
        if (e != i1 && p[e] > p[i2]) i2 = e;
      const float s12 = p[i1] + p[i2] + 1e-20f;
      s_eid[tl][0] = i1;
      s_eid[tl][1] = i2;
      s_wt[tl][0] = p[i1] / s12;
      s_wt[tl][1] = p[i2] / s12;
    }
  }
  __syncthreads();

  if (threadIdx.x < 64) {
    s_rank[threadIdx.x][0] = atomicAdd(&lcnt[s_eid[threadIdx.x][0]], 1);
    s_rank[threadIdx.x][1] = atomicAdd(&lcnt[s_eid[threadIdx.x][1]], 1);
  }
  __syncthreads();
  if (threadIdx.x < 8)
    lbase[threadIdx.x] =
        atomicAdd(&cnt[threadIdx.x * CNT_STRIDE], lcnt[threadIdx.x]);
  __syncthreads();
  if (threadIdx.x < 64) {
    const int t = blockIdx.x * 64 + threadIdx.x;
#pragma unroll
    for (int j = 0; j < 2; j++) {
      const int e = s_eid[threadIdx.x][j];
      const int slot = lbase[e] + s_rank[threadIdx.x][j];
      tok[e * T_TOTAL + slot] = t;
      wtl[e * T_TOTAL + slot] = s_wt[threadIdx.x][j];
      inv[t * 2 + j] = e * T_TOTAL + slot;
    }
  }
}

// ---------------------------------------------------------------------------
// Fused weight prep, single launch. z in [0,9): Wg->Wfu(+0); z in [9,18):
// Wu->Wfu(+16); z in [18,27): Wd->WdT. Scan(cnt)->base folded into block
// (0,0,26) thread 0 (stream-ordered after k_gate).
// 64x64 tiles; float4 loads; bf16x8 16B/lane stores.
// ---------------------------------------------------------------------------
__global__ __launch_bounds__(256) void k_wprep(
    const float* __restrict__ Wg, const float* __restrict__ Wu,
    const float* __restrict__ Wd, const float* __restrict__ sWg,
    const float* __restrict__ sWu, const float* __restrict__ sWd,
    __bf16* __restrict__ Wfu, __bf16* __restrict__ WdT,
    const int* __restrict__ cnt, int* __restrict__ base) {
  if (blockIdx.z == 26 && blockIdx.x == 0 && blockIdx.y == 0 &&
      threadIdx.x == 0) {
    int s = 0;
#pragma unroll
    for (int e = 0; e < 8; e++) {
      base[e] = s;
      s += cnt[e * CNT_STRIDE];
    }
  }

  __shared__ float tile[64][65];
  const int z = blockIdx.z;
  const int t = threadIdx.x;

  if (z < 18) {
    // fused-GU transpose: src fp32 [1024 h][512 i] -> Wfu [1024 f][1024 h]
    if (blockIdx.x >= IDIM / 64) return;
    const int b = (z < 9) ? z : z - 9;
    const int u16off = (z < 9) ? 0 : 16;
    const float* w8 = (z < 9) ? Wg : Wu;
    const float* w1 = (z < 9) ? sWg : sWu;
    const float* src = (b < 8) ? (w8 + (size_t)b * HDIM * IDIM) : w1;
    const int c0 = blockIdx.x * 64, r0 = blockIdx.y * 64;  // c=i, r=h

#pragma unroll
    for (int j = 0; j < 4; j++) {
      const int rr = (t >> 4) + j * 16;
      const int cc = (t & 15) * 4;
      const float4 v =
          *(const float4*)(src + (size_t)(r0 + rr) * IDIM + c0 + cc);
      tile[rr][cc] = v.x;
      tile[rr][cc + 1] = v.y;
      tile[rr][cc + 2] = v.z;
      tile[rr][cc + 3] = v.w;
    }
    __syncthreads();

#pragma unroll
    for (int j = 0; j < 2; j++) {
      const int cidx = (t >> 3) + j * 32;  // i-local
      const int rseg = (t & 7) * 8;        // h-local start
      const int ic = c0 + cidx;
      const int f = 2 * (ic & ~15) + (ic & 15) + u16off;
      bf16x8 v;
#pragma unroll
      for (int k = 0; k < 8; k++) v[k] = (__bf16)tile[rseg + k][cidx];
      *(bf16x8*)(Wfu + (size_t)b * 1024 * HDIM + (size_t)f * HDIM + r0 + rseg) =
          v;
    }
  } else {
    // Wd transpose: src fp32 [512 i][1024 h] -> WdT [1024 h][512 i]
    if (blockIdx.y >= IDIM / 64) return;
    const int b = z - 18;
    const float* src = (b < 8) ? (Wd + (size_t)b * IDIM * HDIM) : sWd;
    const int c0 = blockIdx.x * 64, r0 = blockIdx.y * 64;  // c=h, r=i

#pragma unroll
    for (int j = 0; j < 4; j++) {
      const int rr = (t >> 4) + j * 16;
      const int cc = (t & 15) * 4;
      const float4 v =
          *(const float4*)(src + (size_t)(r0 + rr) * HDIM + c0 + cc);
      tile[rr][cc] = v.x;
      tile[rr][cc + 1] = v.y;
      tile[rr][cc + 2] = v.z;
      tile[rr][cc + 3] = v.w;
    }
    __syncthreads();

#pragma unroll
    for (int j = 0; j < 2; j++) {
      const int cidx = (t >> 3) + j * 32;  // h-local
      const int rseg = (t & 7) * 8;        // i-local start
      bf16x8 v;
#pragma unroll
      for (int k = 0; k < 8; k++) v[k] = (__bf16)tile[rseg + k][cidx];
      *(bf16x8*)(WdT + (size_t)b * HDIM * IDIM + (size_t)(c0 + cidx) * IDIM +
                 r0 + rseg) = v;
    }
  }
}

// ---------------------------------------------------------------------------
// Phase A: one GEMM [slots x 128 fused cols], K=H. zbase selects expert range.
// Output rows PACKED: routed base[e]+slot, shared SH_BASE+slot.
// acc[im][2p]=G, acc[im][2p+1]=U for i-col = (n0+wn)/2 + p*16 + l16.
// ---------------------------------------------------------------------------
__global__ __launch_bounds__(256, 2) void k_gu(
    const __bf16* __restrict__ xb, const __bf16* __restrict__ Wfu,
    const int* __restrict__ tok, const float* __restrict__ wtl,
    const int* __restrict__ cnt, const int* __restrict__ base,
    __bf16* __restrict__ inter, int zbase) {
  const int e = blockIdx.z + zbase;
  const bool se = (e == 8);
  const int cnt_e = se ? T_TOTAL : cnt[e * CNT_STRIDE];
  const int m0 = blockIdx.x * 128;
  if (m0 >= cnt_e) return;  // uniform early-exit before any barrier
  const int rowb = se ? SH_BASE : base[e];

  __shared__ __bf16 sA[128][64];
  __shared__ __bf16 sB[128][64];
  const int tid = threadIdx.x, w = tid >> 6, lane = tid & 63;
  const int n0 = blockIdx.y * 128;  // fused-row base (0..896)
  const int quad = lane >> 4, l16 = lane & 15;
  const int wm = (w & 1) * 64, wn = (w >> 1) * 64;

  // staging: 256 thr x 16B = 4KB/shot = 32 rows of 128B; 4 shots per buffer
  const int sr = tid >> 3;                     // row within shot
  const int scs = ((tid & 7) ^ (sr & 7)) * 8;  // swizzled source offset (elems)
  const __bf16* ap[4];
  const __bf16* bp[4];
#pragma unroll
  for (int sh = 0; sh < 4; sh++) {
    int s = m0 + sh * 32 + sr;
    if (s > cnt_e - 1) s = cnt_e - 1;
    const int t = se ? s : tok[e * T_TOTAL + s];
    ap[sh] = xb + (size_t)t * HDIM + scs;
    bp[sh] = Wfu + ((size_t)e * 1024 + n0 + sh * 32 + sr) * HDIM + scs;
  }
  char* const la = (char*)sA + w * 1024;  // +lane*16 implicit in global_load_lds
  char* const lb = (char*)sB + w * 1024;

  f32x4 acc[4][4];
#pragma unroll
  for (int im = 0; im < 4; im++)
#pragma unroll
    for (int in = 0; in < 4; in++) acc[im][in] = {0.f, 0.f, 0.f, 0.f};

  for (int k = 0; k < HDIM; k += 64) {
    __syncthreads();
#pragma unroll
    for (int sh = 0; sh < 4; sh++) {
      load_lds16(ap[sh], la + sh * 4096);
      load_lds16(bp[sh], lb + sh * 4096);
      ap[sh] += 64;
      bp[sh] += 64;
    }
    __syncthreads();
#pragma unroll
    for (int kh = 0; kh < 2; kh++) {
      bf16x8 af[4], bfr[4];
#pragma unroll
      for (int i = 0; i < 4; i++) {
        const int ra = wm + i * 16 + l16;
        af[i] = *(const bf16x8*)((const char*)sA + ra * 128 +
                                 ((kh * 4 + quad) ^ (ra & 7)) * 16);
        const int rb = wn + i * 16 + l16;
        bfr[i] = *(const bf16x8*)((const char*)sB + rb * 128 +
                                  ((kh * 4 + quad) ^ (rb & 7)) * 16);
      }
#pragma unroll
      for (int im = 0; im < 4; im++)
#pragma unroll
        for (int in = 0; in < 4; in++)
          acc[im][in] = mfma_bf16(af[im], bfr[in], acc[im][in]);
    }
  }

  // epilogue: C/D col=lane&15, row=quad*4+r; G/U pairs in even/odd n-frags
#pragma unroll
  for (int im = 0; im < 4; im++) {
#pragma unroll
    for (int r = 0; r < 4; r++) {
      const int slot = m0 + wm + im * 16 + quad * 4 + r;
      if (slot < cnt_e) {
        const float wt = se ? 1.0f : wtl[e * T_TOTAL + slot];
        __bf16* op =
            inter + ((size_t)(rowb + slot)) * IDIM + ((n0 + wn) >> 1) + l16;
#pragma unroll
        for (int p = 0; p < 2; p++) {
          const float g = acc[im][2 * p][r];
          const float u = acc[im][2 * p + 1][r];
          const float v =
              wt * u * 0.5f * g * (1.0f + erff(g * 0.70710678118654752f));
          op[p * 16] = (__bf16)v;
        }
      }
    }
  }
}

// ---------------------------------------------------------------------------
// Phase B routed, STORE version: per expert e, gathered GEMM over packed inter
// rows [base[e], base[e]+cnt_e) @ Wd[e] -> packed-frag float4 rows of yb:
// yb4[(row*16 + nseg)*16 + l16] = cols {nseg*64 + in*16 + l16 : in=0..3}.
// 16B/lane coalesced; read side uses the identical mapping.
// ---------------------------------------------------------------------------
__global__ __launch_bounds__(256, 2) void k_down_rs(
    const __bf16* __restrict__ inter, const __bf16* __restrict__ WdT,
    const int* __restrict__ cnt, const int* __restrict__ base,
    f32x4* __restrict__ yb4) {
  const int e = blockIdx.z;
  const int cnt_e = cnt[e * CNT_STRIDE];
  const int m0 = blockIdx.x * 128;
  if (m0 >= cnt_e) return;
  const int rowb = base[e];

  __shared__ __bf16 sA[128][64];
  __shared__ __bf16 sB[128][64];
  const int tid = threadIdx.x, w = tid >> 6, lane = tid & 63;
  const int n0 = blockIdx.y * 128;
  const int quad = lane >> 4, l16 = lane & 15;
  const int wm = (w & 1) * 64, wn = (w >> 1) * 64;
  const int nseg = (n0 + wn) >> 6;

  const int sr = tid >> 3;
  const int scs = ((tid & 7) ^ (sr & 7)) * 8;
  const __bf16* ap[4];
  const __bf16* bp[4];
#pragma unroll
  for (int sh = 0; sh < 4; sh++) {
    int s = m0 + sh * 32 + sr;
    if (s > cnt_e - 1) s = cnt_e - 1;
    ap[sh] = inter + (size_t)(rowb + s) * IDIM + scs;
    bp[sh] = WdT + ((size_t)e * HDIM + n0 + sh * 32 + sr) * IDIM + scs;
  }
  char* const la = (char*)sA + w * 1024;
  char* const lb = (char*)sB + w * 1024;

  f32x4 acc[4][4];
#pragma unroll
  for (int im = 0; im < 4; im++)
#pragma unroll
    for (int in = 0; in < 4; in++) acc[im][in] = {0.f, 0.f, 0.f, 0.f};

  for (int k = 0; k < IDIM; k += 64) {
    __syncthreads();
#pragma unroll
    for (int sh = 0; sh < 4; sh++) {
      load_lds16(ap[sh], la + sh * 4096);
      load_lds16(bp[sh], lb + sh * 4096);
      ap[sh] += 64;
      bp[sh] += 64;
    }
    __syncthreads();
#pragma unroll
    for (int kh = 0; kh < 2; kh++) {
      bf16x8 af[4], bfr[4];
#pragma unroll
      for (int i = 0; i < 4; i++) {
        const int ra = wm + i * 16 + l16;
        af[i] = *(const bf16x8*)((const char*)sA + ra * 128 +
                                 ((kh * 4 + quad) ^ (ra & 7)) * 16);
        const int rb = wn + i * 16 + l16;
        bfr[i] = *(const bf16x8*)((const char*)sB + rb * 128 +
                                  ((kh * 4 + quad) ^ (rb & 7)) * 16);
      }
#pragma unroll
      for (int im = 0; im < 4; im++)
#pragma unroll
        for (int in = 0; in < 4; in++)
          acc[im][in] = mfma_bf16(af[im], bfr[in], acc[im][in]);
    }
  }

#pragma unroll
  for (int im = 0; im < 4; im++) {
#pragma unroll
    for (int r = 0; r < 4; r++) {
      const int slot = m0 + wm + im * 16 + quad * 4 + r;
      if (slot < cnt_e) {
        const size_t row = (size_t)(rowb + slot);
        f32x4 v = {acc[im][0][r], acc[im][1][r], acc[im][2][r], acc[im][3][r]};
        yb4[(row * 16 + nseg) * 16 + l16] = v;
      }
    }
  }
}

// ---------------------------------------------------------------------------
// Phase B shared + combine: out[t] = inter[shared] @ sWd + y1(t) + y2(t).
// Routed rows gathered from packed-frag yb4 in the GEMM epilogue; pure stores.
// ---------------------------------------------------------------------------
__global__ __launch_bounds__(256, 2) void k_down_sc(
    const __bf16* __restrict__ iA, const __bf16* __restrict__ wB,
    const f32x4* __restrict__ yb4, const int* __restrict__ inv,
    const int* __restrict__ base, float* __restrict__ out) {
  __shared__ __bf16 sA[128][64];
  __shared__ __bf16 sB[128][64];
  const int tid = threadIdx.x, w = tid >> 6, lane = tid & 63;
  const int m0 = blockIdx.x * 128, n0 = blockIdx.y * 128;
  const int quad = lane >> 4, l16 = lane & 15;
  const int wm = (w & 1) * 64, wn = (w >> 1) * 64;
  const int nseg = (n0 + wn) >> 6;

  const int sr = tid >> 3;
  const int scs = ((tid & 7) ^ (sr & 7)) * 8;
  const __bf16* ap[4];
  const __bf16* bp[4];
#pragma unroll
  for (int sh = 0; sh < 4; sh++) {
    ap[sh] = iA + (size_t)(m0 + sh * 32 + sr) * IDIM + scs;
    bp[sh] = wB + (size_t)(n0 + sh * 32 + sr) * IDIM + scs;
  }
  char* const la = (char*)sA + w * 1024;
  char* const lb = (char*)sB + w * 1024;

  f32x4 acc[4][4];
#pragma unroll
  for (int im = 0; im < 4; im++)
#pragma unroll
    for (int in = 0; in < 4; in++) acc[im][in] = {0.f, 0.f, 0.f, 0.f};

  for (int k = 0; k < IDIM; k += 64) {
    __syncthreads();
#pragma unroll
    for (int sh = 0; sh < 4; sh++) {
      load_lds16(ap[sh], la + sh * 4096);
      load_lds16(bp[sh], lb + sh * 4096);
      ap[sh] += 64;
      bp[sh] += 64;
    }
    __syncthreads();
#pragma unroll
    for (int kh = 0; kh < 2; kh++) {
      bf16x8 af[4], bfr[4];
#pragma unroll
      for (int i = 0; i < 4; i++) {
        const int ra = wm + i * 16 + l16;
        af[i] = *(const bf16x8*)((const char*)sA + ra * 128 +
                                 ((kh * 4 + quad) ^ (ra & 7)) * 16);
        const int rb = wn + i * 16 + l16;
        bfr[i] = *(const bf16x8*)((const char*)sB + rb * 128 +
                                  ((kh * 4 + quad) ^ (rb & 7)) * 16);
      }
#pragma unroll
      for (int im = 0; im < 4; im++)
#pragma unroll
        for (int in = 0; in < 4; in++)
          acc[im][in] = mfma_bf16(af[im], bfr[in], acc[im][in]);
    }
  }

#pragma unroll
  for (int im = 0; im < 4; im++) {
#pragma unroll
    for (int r = 0; r < 4; r++) {
      const int t = m0 + wm + im * 16 + quad * 4 + r;
      const int v1 = inv[2 * t], v2 = inv[2 * t + 1];
      const size_t r1 = base[v1 >> 14] + (v1 & (T_TOTAL - 1));
      const size_t r2 = base[v2 >> 14] + (v2 & (T_TOTAL - 1));
      const f32x4 y1 = yb4[(r1 * 16 + nseg) * 16 + l16];
      const f32x4 y2 = yb4[(r2 * 16 + nseg) * 16 + l16];
      float* op = out + (size_t)t * HDIM + n0 + wn + l16;
#pragma unroll
      for (int in = 0; in < 4; in++)
        op[in * 16] = acc[im][in][r] + y1[in] + y2[in];
    }
  }
}

// ---------------------------------------------------------------------------
// Fallback path (ws too small for yb): shared GEMM plain stores, then routed
// atomic scatter-add on packed inter.
// ---------------------------------------------------------------------------
__global__ __launch_bounds__(256, 2) void k_down_s(const __bf16* __restrict__ iA,
                                                   const __bf16* __restrict__ wB,
                                                   float* __restrict__ out) {
  __shared__ __bf16 sA[128][64];
  __shared__ __bf16 sB[128][64];
  const int tid = threadIdx.x, w = tid >> 6, lane = tid & 63;
  const int m0 = blockIdx.x * 128, n0 = blockIdx.y * 128;
  const int quad = lane >> 4, l16 = lane & 15;
  const int wm = (w & 1) * 64, wn = (w >> 1) * 64;

  const int sr = tid >> 3;
  const int scs = ((tid & 7) ^ (sr & 7)) * 8;
  const __bf16* ap[4];
  const __bf16* bp[4];
#pragma unroll
  for (int sh = 0; sh < 4; sh++) {
    ap[sh] = iA + (size_t)(m0 + sh * 32 + sr) * IDIM + scs;
    bp[sh] = wB + (size_t)(n0 + sh * 32 + sr) * IDIM + scs;
  }
  char* const la = (char*)sA + w * 1024;
  char* const lb = (char*)sB + w * 1024;

  f32x4 acc[4][4];
#pragma unroll
  for (int im = 0; im < 4; im++)
#pragma unroll
    for (int in = 0; in < 4; in++) acc[im][in] = {0.f, 0.f, 0.f, 0.f};

  for (int k = 0; k < IDIM; k += 64) {
    __syncthreads();
#pragma unroll
    for (int sh = 0; sh < 4; sh++) {
      load_lds16(ap[sh], la + sh * 4096);
      load_lds16(bp[sh], lb + sh * 4096);
      ap[sh] += 64;
      bp[sh] += 64;
    }
    __syncthreads();
#pragma unroll
    for (int kh = 0; kh < 2; kh++) {
      bf16x8 af[4], bfr[4];
#pragma unroll
      for (int i = 0; i < 4; i++) {
        const int ra = wm + i * 16 + l16;
        af[i] = *(const bf16x8*)((const char*)sA + ra * 128 +
                                 ((kh * 4 + quad) ^ (ra & 7)) * 16);
        const int rb = wn + i * 16 + l16;
        bfr[i] = *(const bf16x8*)((const char*)sB + rb * 128 +
                                  ((kh * 4 + quad) ^ (rb & 7)) * 16);
      }
#pragma unroll
      for (int im = 0; im < 4; im++)
#pragma unroll
        for (int in = 0; in < 4; in++)
          acc[im][in] = mfma_bf16(af[im], bfr[in], acc[im][in]);
    }
  }

#pragma unroll
  for (int im = 0; im < 4; im++) {
#pragma unroll
    for (int r = 0; r < 4; r++) {
      const int t = m0 + wm + im * 16 + quad * 4 + r;
#pragma unroll
      for (int in = 0; in < 4; in++)
        out[(size_t)t * HDIM + n0 + wn + in * 16 + l16] = acc[im][in][r];
    }
  }
}

__global__ __launch_bounds__(256, 2) void k_down_r(
    const __bf16* __restrict__ inter, const __bf16* __restrict__ WdT,
    const int* __restrict__ tok, const int* __restrict__ cnt,
    const int* __restrict__ base, float* __restrict__ out) {
  const int e = blockIdx.z;
  const int cnt_e = cnt[e * CNT_STRIDE];
  const int m0 = blockIdx.x * 128;
  if (m0 >= cnt_e) return;
  const int rowb = base[e];

  __shared__ __bf16 sA[128][64];
  __shared__ __bf16 sB[128][64];
  const int tid = threadIdx.x, w = tid >> 6, lane = tid & 63;
  const int n0 = blockIdx.y * 128;
  const int quad = lane >> 4, l16 = lane & 15;
  const int wm = (w & 1) * 64, wn = (w >> 1) * 64;

  const int sr = tid >> 3;
  const int scs = ((tid & 7) ^ (sr & 7)) * 8;
  const __bf16* ap[4];
  const __bf16* bp[4];
#pragma unroll
  for (int sh = 0; sh < 4; sh++) {
    int s = m0 + sh * 32 + sr;
    if (s > cnt_e - 1) s = cnt_e - 1;
    ap[sh] = inter + (size_t)(rowb + s) * IDIM + scs;
    bp[sh] = WdT + ((size_t)e * HDIM + n0 + sh * 32 + sr) * IDIM + scs;
  }
  char* const la = (char*)sA + w * 1024;
  char* const lb = (char*)sB + w * 1024;

  f32x4 acc[4][4];
#pragma unroll
  for (int im = 0; im < 4; im++)
#pragma unroll
    for (int in = 0; in < 4; in++) acc[im][in] = {0.f, 0.f, 0.f, 0.f};

  for (int k = 0; k < IDIM; k += 64) {
    __syncthreads();
#pragma unroll
    for (int sh = 0; sh < 4; sh++) {
      load_lds16(ap[sh], la + sh * 4096);
      load_lds16(bp[sh], lb + sh * 4096);
      ap[sh] += 64;
      bp[sh] += 64;
    }
    __syncthreads();
#pragma unroll
    for (int kh = 0; kh < 2; kh++) {
      bf16x8 af[4], bfr[4];
#pragma unroll
      for (int i = 0; i < 4; i++) {
        const int ra = wm + i * 16 + l16;
        af[i] = *(const bf16x8*)((const char*)sA + ra * 128 +
                                 ((kh * 4 + quad) ^ (ra & 7)) * 16);
        const int rb = wn + i * 16 + l16;
        bfr[i] = *(const bf16x8*)((const char*)sB + rb * 128 +
                                  ((kh * 4 + quad) ^ (rb & 7)) * 16);
      }
#pragma unroll
      for (int im = 0; im < 4; im++)
#pragma unroll
        for (int in = 0; in < 4; in++)
          acc[im][in] = mfma_bf16(af[im], bfr[in], acc[im][in]);
    }
  }

#pragma unroll
  for (int im = 0; im < 4; im++) {
#pragma unroll
    for (int r = 0; r < 4; r++) {
      const int slot = m0 + wm + im * 16 + quad * 4 + r;
      if (slot < cnt_e) {
        const int t = tok[e * T_TOTAL + slot];
#pragma unroll
        for (int in = 0; in < 4; in++)
          atomicAdd(&out[(size_t)t * HDIM + n0 + wn + in * 16 + l16],
                    acc[im][in][r]);
      }
    }
  }
}

// ---------------------------------------------------------------------------
extern "C" void kernel_launch(void* const* d_in, const int* in_sizes, int n_in,
                              void* d_out, int out_size, void* d_ws,
                              size_t ws_size, hipStream_t stream) {
  const float* x = (const float*)d_in[0];
  const float* gw = (const float*)d_in[1];
  const float* Wg = (const float*)d_in[2];
  const float* Wu = (const float*)d_in[3];
  const float* Wd = (const float*)d_in[4];
  const float* sWg = (const float*)d_in[5];
  const float* sWu = (const float*)d_in[6];
  const float* sWd = (const float*)d_in[7];
  float* out = (float*)d_out;

  char* ws = (char*)d_ws;
  size_t off = 0;
  auto alloc = [&](size_t n) {
    char* p = ws + off;
    off += (n + 255) & ~(size_t)255;
    return p;
  };
  // --- persistent through phase B ---
  __bf16* WdT = (__bf16*)alloc((size_t)NE * HDIM * IDIM * 2);       // 9.4 MB
  int* tok = (int*)alloc((size_t)8 * T_TOTAL * 4);                  // 512 KB
  float* wtl = (float*)alloc((size_t)8 * T_TOTAL * 4);              // 512 KB
  int* cnt = (int*)alloc(8 * CNT_STRIDE * 4);
  int* inv = (int*)alloc((size_t)T_TOTAL * 2 * 4);                  // 128 KB
  int* base = (int*)alloc(16 * 4);
  __bf16* inter = (__bf16*)alloc((size_t)(3 * T_TOTAL) * IDIM * 2); // 50.3 MB
  const size_t off_persist = off;                                   // ~60.9 MB
  // --- dead after k_gu (yb aliases this region) ---
  __bf16* xb = (__bf16*)alloc((size_t)T_TOTAL * HDIM * 2);          // 33.5 MB
  __bf16* Wfu = (__bf16*)alloc((size_t)NE * 1024 * HDIM * 2);       // 18.9 MB

  // Packed-frag routed down-proj output: 2T rows x H fp32 = 134 MB, aliased
  // over xb+Wfu (stream order: k_down_rs writes only after k_gu's last read).
  const size_t yb_bytes = (size_t)2 * T_TOTAL * HDIM * 4;
  const bool store_path = (off_persist + yb_bytes) <= ws_size;  // needs 195 MB
  f32x4* yb4 = (f32x4*)(ws + off_persist);

  hipMemsetAsync(cnt, 0, 8 * CNT_STRIDE * 4, stream);

  k_gate<<<dim3(T_TOTAL / 64), dim3(256), 0, stream>>>(x, gw, xb, tok, wtl,
                                                       cnt, inv);
  // All weight prep (G-fuse, U-fuse, Wd transpose) + scan in one launch.
  k_wprep<<<dim3(16, 16, 27), dim3(256), 0, stream>>>(Wg, Wu, Wd, sWg, sWu,
                                                      sWd, Wfu, WdT, cnt, base);

  // Phase A: fused GU into packed inter; routed split for profiling
  // visibility (two ~54us halves), then shared.
  k_gu<<<dim3(T_TOTAL / 128, 1024 / 128, 4), dim3(256), 0, stream>>>(
      xb, Wfu, tok, wtl, cnt, base, inter, 0);
  k_gu<<<dim3(T_TOTAL / 128, 1024 / 128, 4), dim3(256), 0, stream>>>(
      xb, Wfu, tok, wtl, cnt, base, inter, 4);
  k_gu<<<dim3(T_TOTAL / 128, 1024 / 128, 1), dim3(256), 0, stream>>>(
      xb, Wfu, tok, wtl, cnt, base, inter, 8);

  if (store_path) {
    // routed experts -> packed-frag yb4 (no atomics), then shared + combine.
    k_down_rs<<<dim3(T_TOTAL / 128, HDIM / 128, 8), dim3(256), 0, stream>>>(
        inter, WdT, cnt, base, yb4);
    k_down_sc<<<dim3(T_TOTAL / 128, HDIM / 128), dim3(256), 0, stream>>>(
        inter + (size_t)SH_BASE * IDIM, WdT + (size_t)8 * HDIM * IDIM, yb4, inv,
        base, out);
  } else {
    // fallback: shared GEMM stores, routed atomic scatter-add
    k_down_s<<<dim3(T_TOTAL / 128, HDIM / 128), dim3(256), 0, stream>>>(
        inter + (size_t)SH_BASE * IDIM, WdT + (size_t)8 * HDIM * IDIM, out);
    k_down_r<<<dim3(T_TOTAL / 128, HDIM / 128, 8), dim3(256), 0, stream>>>(
        inter, WdT, tok, cnt, base, out);
  }
}

// Round 8
// 441.592 us; speedup vs baseline: 1.0190x; 1.0190x over previous
//
#include <hip/hip_runtime.h>
#include <hip/hip_bf16.h>
#include <math.h>

// ---------------------------------------------------------------------------
// DeepseekV2 MoE: T=16384 tokens, H=1024, E=8 routed (top-2) + 1 shared, I=512
// Round 12 (= round 11 resubmitted; previous bench was an infra failure:
// "MI355X container failed twice", no kernel error).
//  - k_gu merged back into ONE launch (z=9). Round-10's split cost +20us
//    (two 64.4us halves vs 108us merged; per-launch tail + wave quantization).
//  - ytok layout: rank j packed in tok bit 14. k_down_rs scatter-WRITES
//    f32x4 fragments to ytok[nseg][2t+j]; k_down_sc reads rows 2t,2t+1
//    sequentially (32KB-contiguous per wave) with no inv/base indirection.
//  - 5 launches: gate, wprep(+scan), gu, down_rs, down_sc.
//  - Atomic fallback retained behind ws_size check.
// ---------------------------------------------------------------------------

#define T_TOTAL 16384
#define HDIM 1024
#define IDIM 512
#define NE 9  // 8 routed + 1 shared (expert index 8)
#define CNT_STRIDE 16
#define SH_BASE 32768  // packed-inter row where shared expert starts

typedef __bf16 bf16x8 __attribute__((ext_vector_type(8)));
typedef float f32x4 __attribute__((ext_vector_type(4)));

typedef __attribute__((address_space(1))) void gvoid_t;
typedef __attribute__((address_space(3))) void lvoid_t;

__device__ __forceinline__ void load_lds16(const void* g, void* l) {
  // 16B/lane; LDS dest = wave-uniform base + lane*16 (global src may scatter)
  __builtin_amdgcn_global_load_lds((const gvoid_t*)g, (lvoid_t*)l, 16, 0, 0);
}

__device__ __forceinline__ f32x4 mfma_bf16(bf16x8 a, bf16x8 b, f32x4 c) {
  return __builtin_amdgcn_mfma_f32_16x16x32_bf16(a, b, c, 0, 0, 0);
}

// ---------------------------------------------------------------------------
// Gate: block-aggregated slot assignment. tok[e*T+slot] = t | (j<<14), where
// j is the assignment rank (0 = top expert, 1 = second). T_TOTAL = 2^14.
// ---------------------------------------------------------------------------
__global__ __launch_bounds__(256) void k_gate(const float* __restrict__ x,
                                              const float* __restrict__ gw,
                                              __bf16* __restrict__ xb,
                                              int* __restrict__ tok,
                                              float* __restrict__ wtl,
                                              int* __restrict__ cnt) {
  __shared__ int s_eid[64][2];
  __shared__ float s_wt[64][2];
  __shared__ int s_rank[64][2];
  __shared__ int lcnt[8];
  __shared__ int lbase[8];
  const int wv = threadIdx.x >> 6, lane = threadIdx.x & 63;
  if (threadIdx.x < 8) lcnt[threadIdx.x] = 0;
  __syncthreads();

  for (int i = 0; i < 16; i++) {
    const int tl = wv * 16 + i;
    const int t = blockIdx.x * 64 + tl;
    const float* xr = x + (size_t)t * HDIM + lane * 16;
    float4 xv[4];
#pragma unroll
    for (int j = 0; j < 4; j++) xv[j] = ((const float4*)xr)[j];

    bf16x8 v0, v1;
#pragma unroll
    for (int j = 0; j < 8; j++) v0[j] = (__bf16)((const float*)xv)[j];
#pragma unroll
    for (int j = 0; j < 8; j++) v1[j] = (__bf16)((const float*)xv)[j + 8];
    bf16x8* xbo = (bf16x8*)(xb + (size_t)t * HDIM + lane * 16);
    xbo[0] = v0;
    xbo[1] = v1;

    float acc[8];
#pragma unroll
    for (int e = 0; e < 8; e++) {
      const float4* gp = (const float4*)(gw + e * HDIM + lane * 16);
      float s = 0.f;
#pragma unroll
      for (int j = 0; j < 4; j++) {
        float4 g = gp[j];
        s += xv[j].x * g.x + xv[j].y * g.y + xv[j].z * g.z + xv[j].w * g.w;
      }
      acc[e] = s;
    }
#pragma unroll
    for (int d = 32; d >= 1; d >>= 1) {
#pragma unroll
      for (int e = 0; e < 8; e++) acc[e] += __shfl_xor(acc[e], d, 64);
    }
    if (lane == 0) {
      float mx = acc[0];
#pragma unroll
      for (int e = 1; e < 8; e++) mx = fmaxf(mx, acc[e]);
      float p[8], Z = 0.f;
#pragma unroll
      for (int e = 0; e < 8; e++) {
        p[e] = expf(acc[e] - mx);
        Z += p[e];
      }
#pragma unroll
      for (int e = 0; e < 8; e++) p[e] /= Z;
      int i1 = 0;
#pragma unroll
      for (int e = 1; e < 8; e++)
        if (p[e] > p[i1]) i1 = e;
      int i2 = (i1 == 0) ? 1 : 0;
#pragma unroll
      for (int e = 0; e < 8; e++)
        if (e != i1 && p[e] > p[i2]) i2 = e;
      const float s12 = p[i1] + p[i2] + 1e-20f;
      s_eid[tl][0] = i1;
      s_eid[tl][1] = i2;
      s_wt[tl][0] = p[i1] / s12;
      s_wt[tl][1] = p[i2] / s12;
    }
  }
  __syncthreads();

  if (threadIdx.x < 64) {
    s_rank[threadIdx.x][0] = atomicAdd(&lcnt[s_eid[threadIdx.x][0]], 1);
    s_rank[threadIdx.x][1] = atomicAdd(&lcnt[s_eid[threadIdx.x][1]], 1);
  }
  __syncthreads();
  if (threadIdx.x < 8)
    lbase[threadIdx.x] =
        atomicAdd(&cnt[threadIdx.x * CNT_STRIDE], lcnt[threadIdx.x]);
  __syncthreads();
  if (threadIdx.x < 64) {
    const int t = blockIdx.x * 64 + threadIdx.x;
#pragma unroll
    for (int j = 0; j < 2; j++) {
      const int e = s_eid[threadIdx.x][j];
      const int slot = lbase[e] + s_rank[threadIdx.x][j];
      tok[e * T_TOTAL + slot] = t | (j << 14);
      wtl[e * T_TOTAL + slot] = s_wt[threadIdx.x][j];
    }
  }
}

// ---------------------------------------------------------------------------
// Fused weight prep, single launch. z in [0,9): Wg->Wfu(+0); z in [9,18):
// Wu->Wfu(+16); z in [18,27): Wd->WdT. Scan(cnt)->base folded into block
// (0,0,26) thread 0 (stream-ordered after k_gate).
// ---------------------------------------------------------------------------
__global__ __launch_bounds__(256) void k_wprep(
    const float* __restrict__ Wg, const float* __restrict__ Wu,
    const float* __restrict__ Wd, const float* __restrict__ sWg,
    const float* __restrict__ sWu, const float* __restrict__ sWd,
    __bf16* __restrict__ Wfu, __bf16* __restrict__ WdT,
    const int* __restrict__ cnt, int* __restrict__ base) {
  if (blockIdx.z == 26 && blockIdx.x == 0 && blockIdx.y == 0 &&
      threadIdx.x == 0) {
    int s = 0;
#pragma unroll
    for (int e = 0; e < 8; e++) {
      base[e] = s;
      s += cnt[e * CNT_STRIDE];
    }
  }

  __shared__ float tile[64][65];
  const int z = blockIdx.z;
  const int t = threadIdx.x;

  if (z < 18) {
    // fused-GU transpose: src fp32 [1024 h][512 i] -> Wfu [1024 f][1024 h]
    if (blockIdx.x >= IDIM / 64) return;
    const int b = (z < 9) ? z : z - 9;
    const int u16off = (z < 9) ? 0 : 16;
    const float* w8 = (z < 9) ? Wg : Wu;
    const float* w1 = (z < 9) ? sWg : sWu;
    const float* src = (b < 8) ? (w8 + (size_t)b * HDIM * IDIM) : w1;
    const int c0 = blockIdx.x * 64, r0 = blockIdx.y * 64;  // c=i, r=h

#pragma unroll
    for (int j = 0; j < 4; j++) {
      const int rr = (t >> 4) + j * 16;
      const int cc = (t & 15) * 4;
      const float4 v =
          *(const float4*)(src + (size_t)(r0 + rr) * IDIM + c0 + cc);
      tile[rr][cc] = v.x;
      tile[rr][cc + 1] = v.y;
      tile[rr][cc + 2] = v.z;
      tile[rr][cc + 3] = v.w;
    }
    __syncthreads();

#pragma unroll
    for (int j = 0; j < 2; j++) {
      const int cidx = (t >> 3) + j * 32;  // i-local
      const int rseg = (t & 7) * 8;        // h-local start
      const int ic = c0 + cidx;
      const int f = 2 * (ic & ~15) + (ic & 15) + u16off;
      bf16x8 v;
#pragma unroll
      for (int k = 0; k < 8; k++) v[k] = (__bf16)tile[rseg + k][cidx];
      *(bf16x8*)(Wfu + (size_t)b * 1024 * HDIM + (size_t)f * HDIM + r0 + rseg) =
          v;
    }
  } else {
    // Wd transpose: src fp32 [512 i][1024 h] -> WdT [1024 h][512 i]
    if (blockIdx.y >= IDIM / 64) return;
    const int b = z - 18;
    const float* src = (b < 8) ? (Wd + (size_t)b * IDIM * HDIM) : sWd;
    const int c0 = blockIdx.x * 64, r0 = blockIdx.y * 64;  // c=h, r=i

#pragma unroll
    for (int j = 0; j < 4; j++) {
      const int rr = (t >> 4) + j * 16;
      const int cc = (t & 15) * 4;
      const float4 v =
          *(const float4*)(src + (size_t)(r0 + rr) * HDIM + c0 + cc);
      tile[rr][cc] = v.x;
      tile[rr][cc + 1] = v.y;
      tile[rr][cc + 2] = v.z;
      tile[rr][cc + 3] = v.w;
    }
    __syncthreads();

#pragma unroll
    for (int j = 0; j < 2; j++) {
      const int cidx = (t >> 3) + j * 32;  // h-local
      const int rseg = (t & 7) * 8;        // i-local start
      bf16x8 v;
#pragma unroll
      for (int k = 0; k < 8; k++) v[k] = (__bf16)tile[rseg + k][cidx];
      *(bf16x8*)(WdT + (size_t)b * HDIM * IDIM + (size_t)(c0 + cidx) * IDIM +
                 r0 + rseg) = v;
    }
  }
}

// ---------------------------------------------------------------------------
// Phase A: one GEMM [slots x 128 fused cols], K=H, all 9 experts in one
// launch (z=0..8). Output rows PACKED: routed base[e]+slot, shared SH_BASE+slot.
// acc[im][2p]=G, acc[im][2p+1]=U for i-col = (n0+wn)/2 + p*16 + l16.
// ---------------------------------------------------------------------------
__global__ __launch_bounds__(256, 2) void k_gu(
    const __bf16* __restrict__ xb, const __bf16* __restrict__ Wfu,
    const int* __restrict__ tok, const float* __restrict__ wtl,
    const int* __restrict__ cnt, const int* __restrict__ base,
    __bf16* __restrict__ inter) {
  const int e = blockIdx.z;
  const bool se = (e == 8);
  const int cnt_e = se ? T_TOTAL : cnt[e * CNT_STRIDE];
  const int m0 = blockIdx.x * 128;
  if (m0 >= cnt_e) return;  // uniform early-exit before any barrier
  const int rowb = se ? SH_BASE : base[e];

  __shared__ __bf16 sA[128][64];
  __shared__ __bf16 sB[128][64];
  const int tid = threadIdx.x, w = tid >> 6, lane = tid & 63;
  const int n0 = blockIdx.y * 128;  // fused-row base (0..896)
  const int quad = lane >> 4, l16 = lane & 15;
  const int wm = (w & 1) * 64, wn = (w >> 1) * 64;

  // staging: 256 thr x 16B = 4KB/shot = 32 rows of 128B; 4 shots per buffer
  const int sr = tid >> 3;                     // row within shot
  const int scs = ((tid & 7) ^ (sr & 7)) * 8;  // swizzled source offset (elems)
  const __bf16* ap[4];
  const __bf16* bp[4];
#pragma unroll
  for (int sh = 0; sh < 4; sh++) {
    int s = m0 + sh * 32 + sr;
    if (s > cnt_e - 1) s = cnt_e - 1;
    const int t = se ? s : (tok[e * T_TOTAL + s] & (T_TOTAL - 1));
    ap[sh] = xb + (size_t)t * HDIM + scs;
    bp[sh] = Wfu + ((size_t)e * 1024 + n0 + sh * 32 + sr) * HDIM + scs;
  }
  char* const la = (char*)sA + w * 1024;  // +lane*16 implicit in global_load_lds
  char* const lb = (char*)sB + w * 1024;

  f32x4 acc[4][4];
#pragma unroll
  for (int im = 0; im < 4; im++)
#pragma unroll
    for (int in = 0; in < 4; in++) acc[im][in] = {0.f, 0.f, 0.f, 0.f};

  for (int k = 0; k < HDIM; k += 64) {
    __syncthreads();
#pragma unroll
    for (int sh = 0; sh < 4; sh++) {
      load_lds16(ap[sh], la + sh * 4096);
      load_lds16(bp[sh], lb + sh * 4096);
      ap[sh] += 64;
      bp[sh] += 64;
    }
    __syncthreads();
#pragma unroll
    for (int kh = 0; kh < 2; kh++) {
      bf16x8 af[4], bfr[4];
#pragma unroll
      for (int i = 0; i < 4; i++) {
        const int ra = wm + i * 16 + l16;
        af[i] = *(const bf16x8*)((const char*)sA + ra * 128 +
                                 ((kh * 4 + quad) ^ (ra & 7)) * 16);
        const int rb = wn + i * 16 + l16;
        bfr[i] = *(const bf16x8*)((const char*)sB + rb * 128 +
                                  ((kh * 4 + quad) ^ (rb & 7)) * 16);
      }
#pragma unroll
      for (int im = 0; im < 4; im++)
#pragma unroll
        for (int in = 0; in < 4; in++)
          acc[im][in] = mfma_bf16(af[im], bfr[in], acc[im][in]);
    }
  }

  // epilogue: C/D col=lane&15, row=quad*4+r; G/U pairs in even/odd n-frags
#pragma unroll
  for (int im = 0; im < 4; im++) {
#pragma unroll
    for (int r = 0; r < 4; r++) {
      const int slot = m0 + wm + im * 16 + quad * 4 + r;
      if (slot < cnt_e) {
        const float wt = se ? 1.0f : wtl[e * T_TOTAL + slot];
        __bf16* op =
            inter + ((size_t)(rowb + slot)) * IDIM + ((n0 + wn) >> 1) + l16;
#pragma unroll
        for (int p = 0; p < 2; p++) {
          const float g = acc[im][2 * p][r];
          const float u = acc[im][2 * p + 1][r];
          const float v =
              wt * u * 0.5f * g * (1.0f + erff(g * 0.70710678118654752f));
          op[p * 16] = (__bf16)v;
        }
      }
    }
  }
}

// ---------------------------------------------------------------------------
// Phase B routed: per expert e, gathered GEMM over packed inter rows @ Wd[e]
// -> token-major ytok: ytok4[(nseg*32768 + 2t+j)*16 + l16] (f32x4/lane,
// 256B contiguous per fragment row). Scattered stores, sequential reads later.
// ---------------------------------------------------------------------------
__global__ __launch_bounds__(256, 2) void k_down_rs(
    const __bf16* __restrict__ inter, const __bf16* __restrict__ WdT,
    const int* __restrict__ tok, const int* __restrict__ cnt,
    const int* __restrict__ base, f32x4* __restrict__ ytok4) {
  const int e = blockIdx.z;
  const int cnt_e = cnt[e * CNT_STRIDE];
  const int m0 = blockIdx.x * 128;
  if (m0 >= cnt_e) return;
  const int rowb = base[e];

  __shared__ __bf16 sA[128][64];
  __shared__ __bf16 sB[128][64];
  const int tid = threadIdx.x, w = tid >> 6, lane = tid & 63;
  const int n0 = blockIdx.y * 128;
  const int quad = lane >> 4, l16 = lane & 15;
  const int wm = (w & 1) * 64, wn = (w >> 1) * 64;
  const int nseg = (n0 + wn) >> 6;

  const int sr = tid >> 3;
  const int scs = ((tid & 7) ^ (sr & 7)) * 8;
  const __bf16* ap[4];
  const __bf16* bp[4];
#pragma unroll
  for (int sh = 0; sh < 4; sh++) {
    int s = m0 + sh * 32 + sr;
    if (s > cnt_e - 1) s = cnt_e - 1;
    ap[sh] = inter + (size_t)(rowb + s) * IDIM + scs;
    bp[sh] = WdT + ((size_t)e * HDIM + n0 + sh * 32 + sr) * IDIM + scs;
  }
  char* const la = (char*)sA + w * 1024;
  char* const lb = (char*)sB + w * 1024;

  f32x4 acc[4][4];
#pragma unroll
  for (int im = 0; im < 4; im++)
#pragma unroll
    for (int in = 0; in < 4; in++) acc[im][in] = {0.f, 0.f, 0.f, 0.f};

  for (int k = 0; k < IDIM; k += 64) {
    __syncthreads();
#pragma unroll
    for (int sh = 0; sh < 4; sh++) {
      load_lds16(ap[sh], la + sh * 4096);
      load_lds16(bp[sh], lb + sh * 4096);
      ap[sh] += 64;
      bp[sh] += 64;
    }
    __syncthreads();
#pragma unroll
    for (int kh = 0; kh < 2; kh++) {
      bf16x8 af[4], bfr[4];
#pragma unroll
      for (int i = 0; i < 4; i++) {
        const int ra = wm + i * 16 + l16;
        af[i] = *(const bf16x8*)((const char*)sA + ra * 128 +
                                 ((kh * 4 + quad) ^ (ra & 7)) * 16);
        const int rb = wn + i * 16 + l16;
        bfr[i] = *(const bf16x8*)((const char*)sB + rb * 128 +
                                  ((kh * 4 + quad) ^ (rb & 7)) * 16);
      }
#pragma unroll
      for (int im = 0; im < 4; im++)
#pragma unroll
        for (int in = 0; in < 4; in++)
          acc[im][in] = mfma_bf16(af[im], bfr[in], acc[im][in]);
    }
  }

#pragma unroll
  for (int im = 0; im < 4; im++) {
#pragma unroll
    for (int r = 0; r < 4; r++) {
      const int slot = m0 + wm + im * 16 + quad * 4 + r;
      if (slot < cnt_e) {
        const int tokv = tok[e * T_TOTAL + slot];
        const size_t row =
            2 * (size_t)(tokv & (T_TOTAL - 1)) + (tokv >> 14);
        f32x4 v = {acc[im][0][r], acc[im][1][r], acc[im][2][r], acc[im][3][r]};
        ytok4[((size_t)nseg * 32768 + row) * 16 + l16] = v;
      }
    }
  }
}

// ---------------------------------------------------------------------------
// Phase B shared + combine: out[t] = inter[shared] @ sWd + ytok[2t] + ytok[2t+1].
// Sequential ytok reads (rows 2t,2t+1 adjacent); pure stores; no indirection.
// ---------------------------------------------------------------------------
__global__ __launch_bounds__(256, 2) void k_down_sc(
    const __bf16* __restrict__ iA, const __bf16* __restrict__ wB,
    const f32x4* __restrict__ ytok4, float* __restrict__ out) {
  __shared__ __bf16 sA[128][64];
  __shared__ __bf16 sB[128][64];
  const int tid = threadIdx.x, w = tid >> 6, lane = tid & 63;
  const int m0 = blockIdx.x * 128, n0 = blockIdx.y * 128;
  const int quad = lane >> 4, l16 = lane & 15;
  const int wm = (w & 1) * 64, wn = (w >> 1) * 64;
  const int nseg = (n0 + wn) >> 6;

  const int sr = tid >> 3;
  const int scs = ((tid & 7) ^ (sr & 7)) * 8;
  const __bf16* ap[4];
  const __bf16* bp[4];
#pragma unroll
  for (int sh = 0; sh < 4; sh++) {
    ap[sh] = iA + (size_t)(m0 + sh * 32 + sr) * IDIM + scs;
    bp[sh] = wB + (size_t)(n0 + sh * 32 + sr) * IDIM + scs;
  }
  char* const la = (char*)sA + w * 1024;
  char* const lb = (char*)sB + w * 1024;

  f32x4 acc[4][4];
#pragma unroll
  for (int im = 0; im < 4; im++)
#pragma unroll
    for (int in = 0; in < 4; in++) acc[im][in] = {0.f, 0.f, 0.f, 0.f};

  for (int k = 0; k < IDIM; k += 64) {
    __syncthreads();
#pragma unroll
    for (int sh = 0; sh < 4; sh++) {
      load_lds16(ap[sh], la + sh * 4096);
      load_lds16(bp[sh], lb + sh * 4096);
      ap[sh] += 64;
      bp[sh] += 64;
    }
    __syncthreads();
#pragma unroll
    for (int kh = 0; kh < 2; kh++) {
      bf16x8 af[4], bfr[4];
#pragma unroll
      for (int i = 0; i < 4; i++) {
        const int ra = wm + i * 16 + l16;
        af[i] = *(const bf16x8*)((const char*)sA + ra * 128 +
                                 ((kh * 4 + quad) ^ (ra & 7)) * 16);
        const int rb = wn + i * 16 + l16;
        bfr[i] = *(const bf16x8*)((const char*)sB + rb * 128 +
                                  ((kh * 4 + quad) ^ (rb & 7)) * 16);
      }
#pragma unroll
      for (int im = 0; im < 4; im++)
#pragma unroll
        for (int in = 0; in < 4; in++)
          acc[im][in] = mfma_bf16(af[im], bfr[in], acc[im][in]);
    }
  }

#pragma unroll
  for (int im = 0; im < 4; im++) {
#pragma unroll
    for (int r = 0; r < 4; r++) {
      const int t = m0 + wm + im * 16 + quad * 4 + r;
      const f32x4 y1 = ytok4[((size_t)nseg * 32768 + 2 * t) * 16 + l16];
      const f32x4 y2 = ytok4[((size_t)nseg * 32768 + 2 * t + 1) * 16 + l16];
      float* op = out + (size_t)t * HDIM + n0 + wn + l16;
#pragma unroll
      for (int in = 0; in < 4; in++)
        op[in * 16] = acc[im][in][r] + y1[in] + y2[in];
    }
  }
}

// ---------------------------------------------------------------------------
// Fallback path (ws too small for ytok): shared GEMM plain stores, then routed
// atomic scatter-add on packed inter.
// ---------------------------------------------------------------------------
__global__ __launch_bounds__(256, 2) void k_down_s(const __bf16* __restrict__ iA,
                                                   const __bf16* __restrict__ wB,
                                                   float* __restrict__ out) {
  __shared__ __bf16 sA[128][64];
  __shared__ __bf16 sB[128][64];
  const int tid = threadIdx.x, w = tid >> 6, lane = tid & 63;
  const int m0 = blockIdx.x * 128, n0 = blockIdx.y * 128;
  const int quad = lane >> 4, l16 = lane & 15;
  const int wm = (w & 1) * 64, wn = (w >> 1) * 64;

  const int sr = tid >> 3;
  const int scs = ((tid & 7) ^ (sr & 7)) * 8;
  const __bf16* ap[4];
  const __bf16* bp[4];
#pragma unroll
  for (int sh = 0; sh < 4; sh++) {
    ap[sh] = iA + (size_t)(m0 + sh * 32 + sr) * IDIM + scs;
    bp[sh] = wB + (size_t)(n0 + sh * 32 + sr) * IDIM + scs;
  }
  char* const la = (char*)sA + w * 1024;
  char* const lb = (char*)sB + w * 1024;

  f32x4 acc[4][4];
#pragma unroll
  for (int im = 0; im < 4; im++)
#pragma unroll
    for (int in = 0; in < 4; in++) acc[im][in] = {0.f, 0.f, 0.f, 0.f};

  for (int k = 0; k < IDIM; k += 64) {
    __syncthreads();
#pragma unroll
    for (int sh = 0; sh < 4; sh++) {
      load_lds16(ap[sh], la + sh * 4096);
      load_lds16(bp[sh], lb + sh * 4096);
      ap[sh] += 64;
      bp[sh] += 64;
    }
    __syncthreads();
#pragma unroll
    for (int kh = 0; kh < 2; kh++) {
      bf16x8 af[4], bfr[4];
#pragma unroll
      for (int i = 0; i < 4; i++) {
        const int ra = wm + i * 16 + l16;
        af[i] = *(const bf16x8*)((const char*)sA + ra * 128 +
                                 ((kh * 4 + quad) ^ (ra & 7)) * 16);
        const int rb = wn + i * 16 + l16;
        bfr[i] = *(const bf16x8*)((const char*)sB + rb * 128 +
                                  ((kh * 4 + quad) ^ (rb & 7)) * 16);
      }
#pragma unroll
      for (int im = 0; im < 4; im++)
#pragma unroll
        for (int in = 0; in < 4; in++)
          acc[im][in] = mfma_bf16(af[im], bfr[in], acc[im][in]);
    }
  }

#pragma unroll
  for (int im = 0; im < 4; im++) {
#pragma unroll
    for (int r = 0; r < 4; r++) {
      const int t = m0 + wm + im * 16 + quad * 4 + r;
#pragma unroll
      for (int in = 0; in < 4; in++)
        out[(size_t)t * HDIM + n0 + wn + in * 16 + l16] = acc[im][in][r];
    }
  }
}

__global__ __launch_bounds__(256, 2) void k_down_r(
    const __bf16* __restrict__ inter, const __bf16* __restrict__ WdT,
    const int* __restrict__ tok, const int* __restrict__ cnt,
    const int* __restrict__ base, float* __restrict__ out) {
  const int e = blockIdx.z;
  const int cnt_e = cnt[e * CNT_STRIDE];
  const int m0 = blockIdx.x * 128;
  if (m0 >= cnt_e) return;
  const int rowb = base[e];

  __shared__ __bf16 sA[128][64];
  __shared__ __bf16 sB[128][64];
  const int tid = threadIdx.x, w = tid >> 6, lane = tid & 63;
  const int n0 = blockIdx.y * 128;
  const int quad = lane >> 4, l16 = lane & 15;
  const int wm = (w & 1) * 64, wn = (w >> 1) * 64;

  const int sr = tid >> 3;
  const int scs = ((tid & 7) ^ (sr & 7)) * 8;
  const __bf16* ap[4];
  const __bf16* bp[4];
#pragma unroll
  for (int sh = 0; sh < 4; sh++) {
    int s = m0 + sh * 32 + sr;
    if (s > cnt_e - 1) s = cnt_e - 1;
    ap[sh] = inter + (size_t)(rowb + s) * IDIM + scs;
    bp[sh] = WdT + ((size_t)e * HDIM + n0 + sh * 32 + sr) * IDIM + scs;
  }
  char* const la = (char*)sA + w * 1024;
  char* const lb = (char*)sB + w * 1024;

  f32x4 acc[4][4];
#pragma unroll
  for (int im = 0; im < 4; im++)
#pragma unroll
    for (int in = 0; in < 4; in++) acc[im][in] = {0.f, 0.f, 0.f, 0.f};

  for (int k = 0; k < IDIM; k += 64) {
    __syncthreads();
#pragma unroll
    for (int sh = 0; sh < 4; sh++) {
      load_lds16(ap[sh], la + sh * 4096);
      load_lds16(bp[sh], lb + sh * 4096);
      ap[sh] += 64;
      bp[sh] += 64;
    }
    __syncthreads();
#pragma unroll
    for (int kh = 0; kh < 2; kh++) {
      bf16x8 af[4], bfr[4];
#pragma unroll
      for (int i = 0; i < 4; i++) {
        const int ra = wm + i * 16 + l16;
        af[i] = *(const bf16x8*)((const char*)sA + ra * 128 +
                                 ((kh * 4 + quad) ^ (ra & 7)) * 16);
        const int rb = wn + i * 16 + l16;
        bfr[i] = *(const bf16x8*)((const char*)sB + rb * 128 +
                                  ((kh * 4 + quad) ^ (rb & 7)) * 16);
      }
#pragma unroll
      for (int im = 0; im < 4; im++)
#pragma unroll
        for (int in = 0; in < 4; in++)
          acc[im][in] = mfma_bf16(af[im], bfr[in], acc[im][in]);
    }
  }

#pragma unroll
  for (int im = 0; im < 4; im++) {
#pragma unroll
    for (int r = 0; r < 4; r++) {
      const int slot = m0 + wm + im * 16 + quad * 4 + r;
      if (slot < cnt_e) {
        const int t = tok[e * T_TOTAL + slot] & (T_TOTAL - 1);
#pragma unroll
        for (int in = 0; in < 4; in++)
          atomicAdd(&out[(size_t)t * HDIM + n0 + wn + in * 16 + l16],
                    acc[im][in][r]);
      }
    }
  }
}

// ---------------------------------------------------------------------------
extern "C" void kernel_launch(void* const* d_in, const int* in_sizes, int n_in,
                              void* d_out, int out_size, void* d_ws,
                              size_t ws_size, hipStream_t stream) {
  const float* x = (const float*)d_in[0];
  const float* gw = (const float*)d_in[1];
  const float* Wg = (const float*)d_in[2];
  const float* Wu = (const float*)d_in[3];
  const float* Wd = (const float*)d_in[4];
  const float* sWg = (const float*)d_in[5];
  const float* sWu = (const float*)d_in[6];
  const float* sWd = (const float*)d_in[7];
  float* out = (float*)d_out;

  char* ws = (char*)d_ws;
  size_t off = 0;
  auto alloc = [&](size_t n) {
    char* p = ws + off;
    off += (n + 255) & ~(size_t)255;
    return p;
  };
  // --- persistent through phase B ---
  __bf16* WdT = (__bf16*)alloc((size_t)NE * HDIM * IDIM * 2);       // 9.4 MB
  int* tok = (int*)alloc((size_t)8 * T_TOTAL * 4);                  // 512 KB
  float* wtl = (float*)alloc((size_t)8 * T_TOTAL * 4);              // 512 KB
  int* cnt = (int*)alloc(8 * CNT_STRIDE * 4);
  int* base = (int*)alloc(16 * 4);
  __bf16* inter = (__bf16*)alloc((size_t)(3 * T_TOTAL) * IDIM * 2); // 50.3 MB
  const size_t off_persist = off;                                   // ~60.8 MB
  // --- dead after k_gu (ytok aliases this region) ---
  __bf16* xb = (__bf16*)alloc((size_t)T_TOTAL * HDIM * 2);          // 33.5 MB
  __bf16* Wfu = (__bf16*)alloc((size_t)NE * 1024 * HDIM * 2);       // 18.9 MB

  // Token-major routed down-proj output: 16 nsegs x 2T rows x 256B = 134 MB,
  // aliased over xb+Wfu (stream order: k_down_rs runs after k_gu).
  const size_t ytok_bytes = (size_t)2 * T_TOTAL * HDIM * 4;
  const bool store_path = (off_persist + ytok_bytes) <= ws_size;  // 195 MB
  f32x4* ytok4 = (f32x4*)(ws + off_persist);

  hipMemsetAsync(cnt, 0, 8 * CNT_STRIDE * 4, stream);

  k_gate<<<dim3(T_TOTAL / 64), dim3(256), 0, stream>>>(x, gw, xb, tok, wtl,
                                                       cnt);
  // All weight prep (G-fuse, U-fuse, Wd transpose) + scan in one launch.
  k_wprep<<<dim3(16, 16, 27), dim3(256), 0, stream>>>(Wg, Wu, Wd, sWg, sWu,
                                                      sWd, Wfu, WdT, cnt, base);

  // Phase A: fused GU into packed inter; all 9 experts in one launch.
  k_gu<<<dim3(T_TOTAL / 128, 1024 / 128, NE), dim3(256), 0, stream>>>(
      xb, Wfu, tok, wtl, cnt, base, inter);

  if (store_path) {
    // routed experts -> token-major ytok (no atomics), then shared + combine.
    k_down_rs<<<dim3(T_TOTAL / 128, HDIM / 128, 8), dim3(256), 0, stream>>>(
        inter, WdT, tok, cnt, base, ytok4);
    k_down_sc<<<dim3(T_TOTAL / 128, HDIM / 128), dim3(256), 0, stream>>>(
        inter + (size_t)SH_BASE * IDIM, WdT + (size_t)8 * HDIM * IDIM, ytok4,
        out);
  } else {
    // fallback: shared GEMM stores, routed atomic scatter-add
    k_down_s<<<dim3(T_TOTAL / 128, HDIM / 128), dim3(256), 0, stream>>>(
        inter + (size_t)SH_BASE * IDIM, WdT + (size_t)8 * HDIM * IDIM, out);
    k_down_r<<<dim3(T_TOTAL / 128, HDIM / 128, 8), dim3(256), 0, stream>>>(
        inter, WdT, tok, cnt, base, out);
  }
}

// Round 9
// 440.781 us; speedup vs baseline: 1.0209x; 1.0018x over previous
//
#include <hip/hip_runtime.h>
#include <hip/hip_bf16.h>
#include <math.h>

// ---------------------------------------------------------------------------
// DeepseekV2 MoE: T=16384 tokens, H=1024, E=8 routed (top-2) + 1 shared, I=512
// Round 13:
//  - Phase B reverted to round-10 layout (ytok token-major scatter-stores in
//    r12 cost ~25us): k_down_rs stores frag-packed f32x4 rows SEQUENTIALLY at
//    row=base[e]+slot; k_down_sc gathers each token's two rows via inv[].
//  - k_gu stays merged (one launch, z=9; confirmed 142 vs 176 split).
//  - Grid-dim swap on gu/rs/sc: N-dim (8 values) is blockIdx.x (fastest) so
//    XCD k owns N-slice k -> 256KB B-panel stays in that XCD's L2
//    (FETCH was 165MB vs 53MB ideal); balanced under early-exit.
//  - 5 launches: gate, wprep(+scan), gu, down_rs, down_sc. Atomic fallback
//    retained behind ws_size check.
// ---------------------------------------------------------------------------

#define T_TOTAL 16384
#define HDIM 1024
#define IDIM 512
#define NE 9  // 8 routed + 1 shared (expert index 8)
#define CNT_STRIDE 16
#define SH_BASE 32768  // packed-inter row where shared expert starts

typedef __bf16 bf16x8 __attribute__((ext_vector_type(8)));
typedef float f32x4 __attribute__((ext_vector_type(4)));

typedef __attribute__((address_space(1))) void gvoid_t;
typedef __attribute__((address_space(3))) void lvoid_t;

__device__ __forceinline__ void load_lds16(const void* g, void* l) {
  // 16B/lane; LDS dest = wave-uniform base + lane*16 (global src may scatter)
  __builtin_amdgcn_global_load_lds((const gvoid_t*)g, (lvoid_t*)l, 16, 0, 0);
}

__device__ __forceinline__ f32x4 mfma_bf16(bf16x8 a, bf16x8 b, f32x4 c) {
  return __builtin_amdgcn_mfma_f32_16x16x32_bf16(a, b, c, 0, 0, 0);
}

// ---------------------------------------------------------------------------
// Gate: block-aggregated slot assignment. Writes inv[t*2+j] = e*16384+slot
// (T_TOTAL = 2^14 -> decode e = v>>14, slot = v&16383).
// ---------------------------------------------------------------------------
__global__ __launch_bounds__(256) void k_gate(const float* __restrict__ x,
                                              const float* __restrict__ gw,
                                              __bf16* __restrict__ xb,
                                              int* __restrict__ tok,
                                              float* __restrict__ wtl,
                                              int* __restrict__ cnt,
                                              int* __restrict__ inv) {
  __shared__ int s_eid[64][2];
  __shared__ float s_wt[64][2];
  __shared__ int s_rank[64][2];
  __shared__ int lcnt[8];
  __shared__ int lbase[8];
  const int wv = threadIdx.x >> 6, lane = threadIdx.x & 63;
  if (threadIdx.x < 8) lcnt[threadIdx.x] = 0;
  __syncthreads();

  for (int i = 0; i < 16; i++) {
    const int tl = wv * 16 + i;
    const int t = blockIdx.x * 64 + tl;
    const float* xr = x + (size_t)t * HDIM + lane * 16;
    float4 xv[4];
#pragma unroll
    for (int j = 0; j < 4; j++) xv[j] = ((const float4*)xr)[j];

    bf16x8 v0, v1;
#pragma unroll
    for (int j = 0; j < 8; j++) v0[j] = (__bf16)((const float*)xv)[j];
#pragma unroll
    for (int j = 0; j < 8; j++) v1[j] = (__bf16)((const float*)xv)[j + 8];
    bf16x8* xbo = (bf16x8*)(xb + (size_t)t * HDIM + lane * 16);
    xbo[0] = v0;
    xbo[1] = v1;

    float acc[8];
#pragma unroll
    for (int e = 0; e < 8; e++) {
      const float4* gp = (const float4*)(gw + e * HDIM + lane * 16);
      float s = 0.f;
#pragma unroll
      for (int j = 0; j < 4; j++) {
        float4 g = gp[j];
        s += xv[j].x * g.x + xv[j].y * g.y + xv[j].z * g.z + xv[j].w * g.w;
      }
      acc[e] = s;
    }
#pragma unroll
    for (int d = 32; d >= 1; d >>= 1) {
#pragma unroll
      for (int e = 0; e < 8; e++) acc[e] += __shfl_xor(acc[e], d, 64);
    }
    if (lane == 0) {
      float mx = acc[0];
#pragma unroll
      for (int e = 1; e < 8; e++) mx = fmaxf(mx, acc[e]);
      float p[8], Z = 0.f;
#pragma unroll
      for (int e = 0; e < 8; e++) {
        p[e] = expf(acc[e] - mx);
        Z += p[e];
      }
#pragma unroll
      for (int e = 0; e < 8; e++) p[e] /= Z;
      int i1 = 0;
#pragma unroll
      for (int e = 1; e < 8; e++)
        if (p[e] > p[i1]) i1 = e;
      int i2 = (i1 == 0) ? 1 : 0;
#pragma unroll
      for (int e = 0; e < 8; e++)
        if (e != i1 && p[e] > p[i2]) i2 = e;
      const float s12 = p[i1] + p[i2] + 1e-20f;
      s_eid[tl][0] = i1;
      s_eid[tl][1] = i2;
      s_wt[tl][0] = p[i1] / s12;
      s_wt[tl][1] = p[i2] / s12;
    }
  }
  __syncthreads();

  if (threadIdx.x < 64) {
    s_rank[threadIdx.x][0] = atomicAdd(&lcnt[s_eid[threadIdx.x][0]], 1);
    s_rank[threadIdx.x][1] = atomicAdd(&lcnt[s_eid[threadIdx.x][1]], 1);
  }
  __syncthreads();
  if (threadIdx.x < 8)
    lbase[threadIdx.x] =
        atomicAdd(&cnt[threadIdx.x * CNT_STRIDE], lcnt[threadIdx.x]);
  __syncthreads();
  if (threadIdx.x < 64) {
    const int t = blockIdx.x * 64 + threadIdx.x;
#pragma unroll
    for (int j = 0; j < 2; j++) {
      const int e = s_eid[threadIdx.x][j];
      const int slot = lbase[e] + s_rank[threadIdx.x][j];
      tok[e * T_TOTAL + slot] = t;
      wtl[e * T_TOTAL + slot] = s_wt[threadIdx.x][j];
      inv[t * 2 + j] = e * T_TOTAL + slot;
    }
  }
}

// ---------------------------------------------------------------------------
// Fused weight prep, single launch. z in [0,9): Wg->Wfu(+0); z in [9,18):
// Wu->Wfu(+16); z in [18,27): Wd->WdT. Scan(cnt)->base folded into block
// (0,0,26) thread 0 (stream-ordered after k_gate).
// ---------------------------------------------------------------------------
__global__ __launch_bounds__(256) void k_wprep(
    const float* __restrict__ Wg, const float* __restrict__ Wu,
    const float* __restrict__ Wd, const float* __restrict__ sWg,
    const float* __restrict__ sWu, const float* __restrict__ sWd,
    __bf16* __restrict__ Wfu, __bf16* __restrict__ WdT,
    const int* __restrict__ cnt, int* __restrict__ base) {
  if (blockIdx.z == 26 && blockIdx.x == 0 && blockIdx.y == 0 &&
      threadIdx.x == 0) {
    int s = 0;
#pragma unroll
    for (int e = 0; e < 8; e++) {
      base[e] = s;
      s += cnt[e * CNT_STRIDE];
    }
  }

  __shared__ float tile[64][65];
  const int z = blockIdx.z;
  const int t = threadIdx.x;

  if (z < 18) {
    // fused-GU transpose: src fp32 [1024 h][512 i] -> Wfu [1024 f][1024 h]
    if (blockIdx.x >= IDIM / 64) return;
    const int b = (z < 9) ? z : z - 9;
    const int u16off = (z < 9) ? 0 : 16;
    const float* w8 = (z < 9) ? Wg : Wu;
    const float* w1 = (z < 9) ? sWg : sWu;
    const float* src = (b < 8) ? (w8 + (size_t)b * HDIM * IDIM) : w1;
    const int c0 = blockIdx.x * 64, r0 = blockIdx.y * 64;  // c=i, r=h

#pragma unroll
    for (int j = 0; j < 4; j++) {
      const int rr = (t >> 4) + j * 16;
      const int cc = (t & 15) * 4;
      const float4 v =
          *(const float4*)(src + (size_t)(r0 + rr) * IDIM + c0 + cc);
      tile[rr][cc] = v.x;
      tile[rr][cc + 1] = v.y;
      tile[rr][cc + 2] = v.z;
      tile[rr][cc + 3] = v.w;
    }
    __syncthreads();

#pragma unroll
    for (int j = 0; j < 2; j++) {
      const int cidx = (t >> 3) + j * 32;  // i-local
      const int rseg = (t & 7) * 8;        // h-local start
      const int ic = c0 + cidx;
      const int f = 2 * (ic & ~15) + (ic & 15) + u16off;
      bf16x8 v;
#pragma unroll
      for (int k = 0; k < 8; k++) v[k] = (__bf16)tile[rseg + k][cidx];
      *(bf16x8*)(Wfu + (size_t)b * 1024 * HDIM + (size_t)f * HDIM + r0 + rseg) =
          v;
    }
  } else {
    // Wd transpose: src fp32 [512 i][1024 h] -> WdT [1024 h][512 i]
    if (blockIdx.y >= IDIM / 64) return;
    const int b = z - 18;
    const float* src = (b < 8) ? (Wd + (size_t)b * IDIM * HDIM) : sWd;
    const int c0 = blockIdx.x * 64, r0 = blockIdx.y * 64;  // c=h, r=i

#pragma unroll
    for (int j = 0; j < 4; j++) {
      const int rr = (t >> 4) + j * 16;
      const int cc = (t & 15) * 4;
      const float4 v =
          *(const float4*)(src + (size_t)(r0 + rr) * HDIM + c0 + cc);
      tile[rr][cc] = v.x;
      tile[rr][cc + 1] = v.y;
      tile[rr][cc + 2] = v.z;
      tile[rr][cc + 3] = v.w;
    }
    __syncthreads();

#pragma unroll
    for (int j = 0; j < 2; j++) {
      const int cidx = (t >> 3) + j * 32;  // h-local
      const int rseg = (t & 7) * 8;        // i-local start
      bf16x8 v;
#pragma unroll
      for (int k = 0; k < 8; k++) v[k] = (__bf16)tile[rseg + k][cidx];
      *(bf16x8*)(WdT + (size_t)b * HDIM * IDIM + (size_t)(c0 + cidx) * IDIM +
                 r0 + rseg) = v;
    }
  }
}

// ---------------------------------------------------------------------------
// Phase A: one GEMM [slots x 128 fused cols], K=H, all 9 experts, one launch.
// GRID SWAPPED: blockIdx.x = N-tile (8 values, dispatch-fastest -> each XCD
// owns one N-slice, B-panel L2-resident), blockIdx.y = M-tile.
// Output rows PACKED: routed base[e]+slot, shared SH_BASE+slot.
// acc[im][2p]=G, acc[im][2p+1]=U for i-col = (n0+wn)/2 + p*16 + l16.
// ---------------------------------------------------------------------------
__global__ __launch_bounds__(256, 2) void k_gu(
    const __bf16* __restrict__ xb, const __bf16* __restrict__ Wfu,
    const int* __restrict__ tok, const float* __restrict__ wtl,
    const int* __restrict__ cnt, const int* __restrict__ base,
    __bf16* __restrict__ inter) {
  const int e = blockIdx.z;
  const bool se = (e == 8);
  const int cnt_e = se ? T_TOTAL : cnt[e * CNT_STRIDE];
  const int m0 = blockIdx.y * 128;
  if (m0 >= cnt_e) return;  // uniform early-exit before any barrier
  const int rowb = se ? SH_BASE : base[e];

  __shared__ __bf16 sA[128][64];
  __shared__ __bf16 sB[128][64];
  const int tid = threadIdx.x, w = tid >> 6, lane = tid & 63;
  const int n0 = blockIdx.x * 128;  // fused-row base (0..896)
  const int quad = lane >> 4, l16 = lane & 15;
  const int wm = (w & 1) * 64, wn = (w >> 1) * 64;

  // staging: 256 thr x 16B = 4KB/shot = 32 rows of 128B; 4 shots per buffer
  const int sr = tid >> 3;                     // row within shot
  const int scs = ((tid & 7) ^ (sr & 7)) * 8;  // swizzled source offset (elems)
  const __bf16* ap[4];
  const __bf16* bp[4];
#pragma unroll
  for (int sh = 0; sh < 4; sh++) {
    int s = m0 + sh * 32 + sr;
    if (s > cnt_e - 1) s = cnt_e - 1;
    const int t = se ? s : tok[e * T_TOTAL + s];
    ap[sh] = xb + (size_t)t * HDIM + scs;
    bp[sh] = Wfu + ((size_t)e * 1024 + n0 + sh * 32 + sr) * HDIM + scs;
  }
  char* const la = (char*)sA + w * 1024;  // +lane*16 implicit in global_load_lds
  char* const lb = (char*)sB + w * 1024;

  f32x4 acc[4][4];
#pragma unroll
  for (int im = 0; im < 4; im++)
#pragma unroll
    for (int in = 0; in < 4; in++) acc[im][in] = {0.f, 0.f, 0.f, 0.f};

  for (int k = 0; k < HDIM; k += 64) {
    __syncthreads();
#pragma unroll
    for (int sh = 0; sh < 4; sh++) {
      load_lds16(ap[sh], la + sh * 4096);
      load_lds16(bp[sh], lb + sh * 4096);
      ap[sh] += 64;
      bp[sh] += 64;
    }
    __syncthreads();
#pragma unroll
    for (int kh = 0; kh < 2; kh++) {
      bf16x8 af[4], bfr[4];
#pragma unroll
      for (int i = 0; i < 4; i++) {
        const int ra = wm + i * 16 + l16;
        af[i] = *(const bf16x8*)((const char*)sA + ra * 128 +
                                 ((kh * 4 + quad) ^ (ra & 7)) * 16);
        const int rb = wn + i * 16 + l16;
        bfr[i] = *(const bf16x8*)((const char*)sB + rb * 128 +
                                  ((kh * 4 + quad) ^ (rb & 7)) * 16);
      }
#pragma unroll
      for (int im = 0; im < 4; im++)
#pragma unroll
        for (int in = 0; in < 4; in++)
          acc[im][in] = mfma_bf16(af[im], bfr[in], acc[im][in]);
    }
  }

  // epilogue: C/D col=lane&15, row=quad*4+r; G/U pairs in even/odd n-frags
#pragma unroll
  for (int im = 0; im < 4; im++) {
#pragma unroll
    for (int r = 0; r < 4; r++) {
      const int slot = m0 + wm + im * 16 + quad * 4 + r;
      if (slot < cnt_e) {
        const float wt = se ? 1.0f : wtl[e * T_TOTAL + slot];
        __bf16* op =
            inter + ((size_t)(rowb + slot)) * IDIM + ((n0 + wn) >> 1) + l16;
#pragma unroll
        for (int p = 0; p < 2; p++) {
          const float g = acc[im][2 * p][r];
          const float u = acc[im][2 * p + 1][r];
          const float v =
              wt * u * 0.5f * g * (1.0f + erff(g * 0.70710678118654752f));
          op[p * 16] = (__bf16)v;
        }
      }
    }
  }
}

// ---------------------------------------------------------------------------
// Phase B routed: per expert e, gathered GEMM over packed inter rows @ Wd[e]
// -> frag-packed f32x4 rows of yb, SEQUENTIAL stores at row=base[e]+slot:
// yb4[(row*16 + nseg)*16 + l16] = cols {nseg*64 + in*16 + l16}.
// GRID SWAPPED (x = N-tile, y = M-tile).
// ---------------------------------------------------------------------------
__global__ __launch_bounds__(256, 2) void k_down_rs(
    const __bf16* __restrict__ inter, const __bf16* __restrict__ WdT,
    const int* __restrict__ cnt, const int* __restrict__ base,
    f32x4* __restrict__ yb4) {
  const int e = blockIdx.z;
  const int cnt_e = cnt[e * CNT_STRIDE];
  const int m0 = blockIdx.y * 128;
  if (m0 >= cnt_e) return;
  const int rowb = base[e];

  __shared__ __bf16 sA[128][64];
  __shared__ __bf16 sB[128][64];
  const int tid = threadIdx.x, w = tid >> 6, lane = tid & 63;
  const int n0 = blockIdx.x * 128;
  const int quad = lane >> 4, l16 = lane & 15;
  const int wm = (w & 1) * 64, wn = (w >> 1) * 64;
  const int nseg = (n0 + wn) >> 6;

  const int sr = tid >> 3;
  const int scs = ((tid & 7) ^ (sr & 7)) * 8;
  const __bf16* ap[4];
  const __bf16* bp[4];
#pragma unroll
  for (int sh = 0; sh < 4; sh++) {
    int s = m0 + sh * 32 + sr;
    if (s > cnt_e - 1) s = cnt_e - 1;
    ap[sh] = inter + (size_t)(rowb + s) * IDIM + scs;
    bp[sh] = WdT + ((size_t)e * HDIM + n0 + sh * 32 + sr) * IDIM + scs;
  }
  char* const la = (char*)sA + w * 1024;
  char* const lb = (char*)sB + w * 1024;

  f32x4 acc[4][4];
#pragma unroll
  for (int im = 0; im < 4; im++)
#pragma unroll
    for (int in = 0; in < 4; in++) acc[im][in] = {0.f, 0.f, 0.f, 0.f};

  for (int k = 0; k < IDIM; k += 64) {
    __syncthreads();
#pragma unroll
    for (int sh = 0; sh < 4; sh++) {
      load_lds16(ap[sh], la + sh * 4096);
      load_lds16(bp[sh], lb + sh * 4096);
      ap[sh] += 64;
      bp[sh] += 64;
    }
    __syncthreads();
#pragma unroll
    for (int kh = 0; kh < 2; kh++) {
      bf16x8 af[4], bfr[4];
#pragma unroll
      for (int i = 0; i < 4; i++) {
        const int ra = wm + i * 16 + l16;
        af[i] = *(const bf16x8*)((const char*)sA + ra * 128 +
                                 ((kh * 4 + quad) ^ (ra & 7)) * 16);
        const int rb = wn + i * 16 + l16;
        bfr[i] = *(const bf16x8*)((const char*)sB + rb * 128 +
                                  ((kh * 4 + quad) ^ (rb & 7)) * 16);
      }
#pragma unroll
      for (int im = 0; im < 4; im++)
#pragma unroll
        for (int in = 0; in < 4; in++)
          acc[im][in] = mfma_bf16(af[im], bfr[in], acc[im][in]);
    }
  }

#pragma unroll
  for (int im = 0; im < 4; im++) {
#pragma unroll
    for (int r = 0; r < 4; r++) {
      const int slot = m0 + wm + im * 16 + quad * 4 + r;
      if (slot < cnt_e) {
        const size_t row = (size_t)(rowb + slot);
        f32x4 v = {acc[im][0][r], acc[im][1][r], acc[im][2][r], acc[im][3][r]};
        yb4[(row * 16 + nseg) * 16 + l16] = v;
      }
    }
  }
}

// ---------------------------------------------------------------------------
// Phase B shared + combine: out[t] = inter[shared] @ sWd + yb[r1(t)] + yb[r2(t)].
// Routed rows gathered from frag-packed yb4 via inv[] in the GEMM epilogue.
// GRID SWAPPED (x = N-tile, y = M-tile).
// ---------------------------------------------------------------------------
__global__ __launch_bounds__(256, 2) void k_down_sc(
    const __bf16* __restrict__ iA, const __bf16* __restrict__ wB,
    const f32x4* __restrict__ yb4, const int* __restrict__ inv,
    const int* __restrict__ base, float* __restrict__ out) {
  __shared__ __bf16 sA[128][64];
  __shared__ __bf16 sB[128][64];
  const int tid = threadIdx.x, w = tid >> 6, lane = tid & 63;
  const int m0 = blockIdx.y * 128, n0 = blockIdx.x * 128;
  const int quad = lane >> 4, l16 = lane & 15;
  const int wm = (w & 1) * 64, wn = (w >> 1) * 64;
  const int nseg = (n0 + wn) >> 6;

  const int sr = tid >> 3;
  const int scs = ((tid & 7) ^ (sr & 7)) * 8;
  const __bf16* ap[4];
  const __bf16* bp[4];
#pragma unroll
  for (int sh = 0; sh < 4; sh++) {
    ap[sh] = iA + (size_t)(m0 + sh * 32 + sr) * IDIM + scs;
    bp[sh] = wB + (size_t)(n0 + sh * 32 + sr) * IDIM + scs;
  }
  char* const la = (char*)sA + w * 1024;
  char* const lb = (char*)sB + w * 1024;

  f32x4 acc[4][4];
#pragma unroll
  for (int im = 0; im < 4; im++)
#pragma unroll
    for (int in = 0; in < 4; in++) acc[im][in] = {0.f, 0.f, 0.f, 0.f};

  for (int k = 0; k < IDIM; k += 64) {
    __syncthreads();
#pragma unroll
    for (int sh = 0; sh < 4; sh++) {
      load_lds16(ap[sh], la + sh * 4096);
      load_lds16(bp[sh], lb + sh * 4096);
      ap[sh] += 64;
      bp[sh] += 64;
    }
    __syncthreads();
#pragma unroll
    for (int kh = 0; kh < 2; kh++) {
      bf16x8 af[4], bfr[4];
#pragma unroll
      for (int i = 0; i < 4; i++) {
        const int ra = wm + i * 16 + l16;
        af[i] = *(const bf16x8*)((const char*)sA + ra * 128 +
                                 ((kh * 4 + quad) ^ (ra & 7)) * 16);
        const int rb = wn + i * 16 + l16;
        bfr[i] = *(const bf16x8*)((const char*)sB + rb * 128 +
                                  ((kh * 4 + quad) ^ (rb & 7)) * 16);
      }
#pragma unroll
      for (int im = 0; im < 4; im++)
#pragma unroll
        for (int in = 0; in < 4; in++)
          acc[im][in] = mfma_bf16(af[im], bfr[in], acc[im][in]);
    }
  }

#pragma unroll
  for (int im = 0; im < 4; im++) {
#pragma unroll
    for (int r = 0; r < 4; r++) {
      const int t = m0 + wm + im * 16 + quad * 4 + r;
      const int v1 = inv[2 * t], v2 = inv[2 * t + 1];
      const size_t r1 = base[v1 >> 14] + (v1 & (T_TOTAL - 1));
      const size_t r2 = base[v2 >> 14] + (v2 & (T_TOTAL - 1));
      const f32x4 y1 = yb4[(r1 * 16 + nseg) * 16 + l16];
      const f32x4 y2 = yb4[(r2 * 16 + nseg) * 16 + l16];
      float* op = out + (size_t)t * HDIM + n0 + wn + l16;
#pragma unroll
      for (int in = 0; in < 4; in++)
        op[in * 16] = acc[im][in][r] + y1[in] + y2[in];
    }
  }
}

// ---------------------------------------------------------------------------
// Fallback path (ws too small for yb): shared GEMM plain stores, then routed
// atomic scatter-add on packed inter.
// ---------------------------------------------------------------------------
__global__ __launch_bounds__(256, 2) void k_down_s(const __bf16* __restrict__ iA,
                                                   const __bf16* __restrict__ wB,
                                                   float* __restrict__ out) {
  __shared__ __bf16 sA[128][64];
  __shared__ __bf16 sB[128][64];
  const int tid = threadIdx.x, w = tid >> 6, lane = tid & 63;
  const int m0 = blockIdx.x * 128, n0 = blockIdx.y * 128;
  const int quad = lane >> 4, l16 = lane & 15;
  const int wm = (w & 1) * 64, wn = (w >> 1) * 64;

  const int sr = tid >> 3;
  const int scs = ((tid & 7) ^ (sr & 7)) * 8;
  const __bf16* ap[4];
  const __bf16* bp[4];
#pragma unroll
  for (int sh = 0; sh < 4; sh++) {
    ap[sh] = iA + (size_t)(m0 + sh * 32 + sr) * IDIM + scs;
    bp[sh] = wB + (size_t)(n0 + sh * 32 + sr) * IDIM + scs;
  }
  char* const la = (char*)sA + w * 1024;
  char* const lb = (char*)sB + w * 1024;

  f32x4 acc[4][4];
#pragma unroll
  for (int im = 0; im < 4; im++)
#pragma unroll
    for (int in = 0; in < 4; in++) acc[im][in] = {0.f, 0.f, 0.f, 0.f};

  for (int k = 0; k < IDIM; k += 64) {
    __syncthreads();
#pragma unroll
    for (int sh = 0; sh < 4; sh++) {
      load_lds16(ap[sh], la + sh * 4096);
      load_lds16(bp[sh], lb + sh * 4096);
      ap[sh] += 64;
      bp[sh] += 64;
    }
    __syncthreads();
#pragma unroll
    for (int kh = 0; kh < 2; kh++) {
      bf16x8 af[4], bfr[4];
#pragma unroll
      for (int i = 0; i < 4; i++) {
        const int ra = wm + i * 16 + l16;
        af[i] = *(const bf16x8*)((const char*)sA + ra * 128 +
                                 ((kh * 4 + quad) ^ (ra & 7)) * 16);
        const int rb = wn + i * 16 + l16;
        bfr[i] = *(const bf16x8*)((const char*)sB + rb * 128 +
                                  ((kh * 4 + quad) ^ (rb & 7)) * 16);
      }
#pragma unroll
      for (int im = 0; im < 4; im++)
#pragma unroll
        for (int in = 0; in < 4; in++)
          acc[im][in] = mfma_bf16(af[im], bfr[in], acc[im][in]);
    }
  }

#pragma unroll
  for (int im = 0; im < 4; im++) {
#pragma unroll
    for (int r = 0; r < 4; r++) {
      const int t = m0 + wm + im * 16 + quad * 4 + r;
#pragma unroll
      for (int in = 0; in < 4; in++)
        out[(size_t)t * HDIM + n0 + wn + in * 16 + l16] = acc[im][in][r];
    }
  }
}

__global__ __launch_bounds__(256, 2) void k_down_r(
    const __bf16* __restrict__ inter, const __bf16* __restrict__ WdT,
    const int* __restrict__ tok, const int* __restrict__ cnt,
    const int* __restrict__ base, float* __restrict__ out) {
  const int e = blockIdx.z;
  const int cnt_e = cnt[e * CNT_STRIDE];
  const int m0 = blockIdx.x * 128;
  if (m0 >= cnt_e) return;
  const int rowb = base[e];

  __shared__ __bf16 sA[128][64];
  __shared__ __bf16 sB[128][64];
  const int tid = threadIdx.x, w = tid >> 6, lane = tid & 63;
  const int n0 = blockIdx.y * 128;
  const int quad = lane >> 4, l16 = lane & 15;
  const int wm = (w & 1) * 64, wn = (w >> 1) * 64;

  const int sr = tid >> 3;
  const int scs = ((tid & 7) ^ (sr & 7)) * 8;
  const __bf16* ap[4];
  const __bf16* bp[4];
#pragma unroll
  for (int sh = 0; sh < 4; sh++) {
    int s = m0 + sh * 32 + sr;
    if (s > cnt_e - 1) s = cnt_e - 1;
    ap[sh] = inter + (size_t)(rowb + s) * IDIM + scs;
    bp[sh] = WdT + ((size_t)e * HDIM + n0 + sh * 32 + sr) * IDIM + scs;
  }
  char* const la = (char*)sA + w * 1024;
  char* const lb = (char*)sB + w * 1024;

  f32x4 acc[4][4];
#pragma unroll
  for (int im = 0; im < 4; im++)
#pragma unroll
    for (int in = 0; in < 4; in++) acc[im][in] = {0.f, 0.f, 0.f, 0.f};

  for (int k = 0; k < IDIM; k += 64) {
    __syncthreads();
#pragma unroll
    for (int sh = 0; sh < 4; sh++) {
      load_lds16(ap[sh], la + sh * 4096);
      load_lds16(bp[sh], lb + sh * 4096);
      ap[sh] += 64;
      bp[sh] += 64;
    }
    __syncthreads();
#pragma unroll
    for (int kh = 0; kh < 2; kh++) {
      bf16x8 af[4], bfr[4];
#pragma unroll
      for (int i = 0; i < 4; i++) {
        const int ra = wm + i * 16 + l16;
        af[i] = *(const bf16x8*)((const char*)sA + ra * 128 +
                                 ((kh * 4 + quad) ^ (ra & 7)) * 16);
        const int rb = wn + i * 16 + l16;
        bfr[i] = *(const bf16x8*)((const char*)sB + rb * 128 +
                                  ((kh * 4 + quad) ^ (rb & 7)) * 16);
      }
#pragma unroll
      for (int im = 0; im < 4; im++)
#pragma unroll
        for (int in = 0; in < 4; in++)
          acc[im][in] = mfma_bf16(af[im], bfr[in], acc[im][in]);
    }
  }

#pragma unroll
  for (int im = 0; im < 4; im++) {
#pragma unroll
    for (int r = 0; r < 4; r++) {
      const int slot = m0 + wm + im * 16 + quad * 4 + r;
      if (slot < cnt_e) {
        const int t = tok[e * T_TOTAL + slot];
#pragma unroll
        for (int in = 0; in < 4; in++)
          atomicAdd(&out[(size_t)t * HDIM + n0 + wn + in * 16 + l16],
                    acc[im][in][r]);
      }
    }
  }
}

// ---------------------------------------------------------------------------
extern "C" void kernel_launch(void* const* d_in, const int* in_sizes, int n_in,
                              void* d_out, int out_size, void* d_ws,
                              size_t ws_size, hipStream_t stream) {
  const float* x = (const float*)d_in[0];
  const float* gw = (const float*)d_in[1];
  const float* Wg = (const float*)d_in[2];
  const float* Wu = (const float*)d_in[3];
  const float* Wd = (const float*)d_in[4];
  const float* sWg = (const float*)d_in[5];
  const float* sWu = (const float*)d_in[6];
  const float* sWd = (const float*)d_in[7];
  float* out = (float*)d_out;

  char* ws = (char*)d_ws;
  size_t off = 0;
  auto alloc = [&](size_t n) {
    char* p = ws + off;
    off += (n + 255) & ~(size_t)255;
    return p;
  };
  // --- persistent through phase B ---
  __bf16* WdT = (__bf16*)alloc((size_t)NE * HDIM * IDIM * 2);       // 9.4 MB
  int* tok = (int*)alloc((size_t)8 * T_TOTAL * 4);                  // 512 KB
  float* wtl = (float*)alloc((size_t)8 * T_TOTAL * 4);              // 512 KB
  int* cnt = (int*)alloc(8 * CNT_STRIDE * 4);
  int* inv = (int*)alloc((size_t)T_TOTAL * 2 * 4);                  // 128 KB
  int* base = (int*)alloc(16 * 4);
  __bf16* inter = (__bf16*)alloc((size_t)(3 * T_TOTAL) * IDIM * 2); // 50.3 MB
  const size_t off_persist = off;                                   // ~60.9 MB
  // --- dead after k_gu (yb aliases this region) ---
  __bf16* xb = (__bf16*)alloc((size_t)T_TOTAL * HDIM * 2);          // 33.5 MB
  __bf16* Wfu = (__bf16*)alloc((size_t)NE * 1024 * HDIM * 2);       // 18.9 MB

  // Frag-packed routed down-proj output: 2T rows x H fp32 = 134 MB, aliased
  // over xb+Wfu (stream order: k_down_rs runs after k_gu's last read).
  const size_t yb_bytes = (size_t)2 * T_TOTAL * HDIM * 4;
  const bool store_path = (off_persist + yb_bytes) <= ws_size;  // needs 195 MB
  f32x4* yb4 = (f32x4*)(ws + off_persist);

  hipMemsetAsync(cnt, 0, 8 * CNT_STRIDE * 4, stream);

  k_gate<<<dim3(T_TOTAL / 64), dim3(256), 0, stream>>>(x, gw, xb, tok, wtl,
                                                       cnt, inv);
  // All weight prep (G-fuse, U-fuse, Wd transpose) + scan in one launch.
  k_wprep<<<dim3(16, 16, 27), dim3(256), 0, stream>>>(Wg, Wu, Wd, sWg, sWu,
                                                      sWd, Wfu, WdT, cnt, base);

  // Phase A: fused GU into packed inter; grid swapped (x = N-tile, 8 values).
  k_gu<<<dim3(1024 / 128, T_TOTAL / 128, NE), dim3(256), 0, stream>>>(
      xb, Wfu, tok, wtl, cnt, base, inter);

  if (store_path) {
    // routed experts -> frag-packed yb4 (sequential stores), then shared +
    // inv-gathered combine.
    k_down_rs<<<dim3(HDIM / 128, T_TOTAL / 128, 8), dim3(256), 0, stream>>>(
        inter, WdT, cnt, base, yb4);
    k_down_sc<<<dim3(HDIM / 128, T_TOTAL / 128), dim3(256), 0, stream>>>(
        inter + (size_t)SH_BASE * IDIM, WdT + (size_t)8 * HDIM * IDIM, yb4, inv,
        base, out);
  } else {
    // fallback: shared GEMM stores, routed atomic scatter-add
    k_down_s<<<dim3(T_TOTAL / 128, HDIM / 128), dim3(256), 0, stream>>>(
        inter + (size_t)SH_BASE * IDIM, WdT + (size_t)8 * HDIM * IDIM, out);
    k_down_r<<<dim3(T_TOTAL / 128, HDIM / 128, 8), dim3(256), 0, stream>>>(
        inter, WdT, tok, cnt, base, out);
  }
}

// Round 10
// 420.985 us; speedup vs baseline: 1.0689x; 1.0470x over previous
//
#include <hip/hip_runtime.h>
#include <hip/hip_bf16.h>
#include <math.h>

// ---------------------------------------------------------------------------
// DeepseekV2 MoE: T=16384 tokens, H=1024, E=8 routed (top-2) + 1 shared, I=512
// Round 14: isolate the grid-orientation variable.
//  - k_gu KEEPS N-fastest grid (r12->r13 A/B: 142.7 -> 135.6us; FETCH rose
//    165->392MB but kernel is latency- not BW-bound at 3.3TB/s).
//  - k_down_rs / k_down_sc REVERT to M-fastest grid: their A-operand (inter,
//    50MB) was being re-read by all 8 XCDs under N-fastest with only K=512
//    of compute to hide it (r13 non-gu +28us vs r9).
//  - Everything else unchanged from r13 (r10 yb4 frag-packed layout, merged
//    gu, wprep+scan fusion, 5 launches, atomic fallback).
// ---------------------------------------------------------------------------

#define T_TOTAL 16384
#define HDIM 1024
#define IDIM 512
#define NE 9  // 8 routed + 1 shared (expert index 8)
#define CNT_STRIDE 16
#define SH_BASE 32768  // packed-inter row where shared expert starts

typedef __bf16 bf16x8 __attribute__((ext_vector_type(8)));
typedef float f32x4 __attribute__((ext_vector_type(4)));

typedef __attribute__((address_space(1))) void gvoid_t;
typedef __attribute__((address_space(3))) void lvoid_t;

__device__ __forceinline__ void load_lds16(const void* g, void* l) {
  // 16B/lane; LDS dest = wave-uniform base + lane*16 (global src may scatter)
  __builtin_amdgcn_global_load_lds((const gvoid_t*)g, (lvoid_t*)l, 16, 0, 0);
}

__device__ __forceinline__ f32x4 mfma_bf16(bf16x8 a, bf16x8 b, f32x4 c) {
  return __builtin_amdgcn_mfma_f32_16x16x32_bf16(a, b, c, 0, 0, 0);
}

// ---------------------------------------------------------------------------
// Gate: block-aggregated slot assignment. Writes inv[t*2+j] = e*16384+slot
// (T_TOTAL = 2^14 -> decode e = v>>14, slot = v&16383).
// ---------------------------------------------------------------------------
__global__ __launch_bounds__(256) void k_gate(const float* __restrict__ x,
                                              const float* __restrict__ gw,
                                              __bf16* __restrict__ xb,
                                              int* __restrict__ tok,
                                              float* __restrict__ wtl,
                                              int* __restrict__ cnt,
                                              int* __restrict__ inv) {
  __shared__ int s_eid[64][2];
  __shared__ float s_wt[64][2];
  __shared__ int s_rank[64][2];
  __shared__ int lcnt[8];
  __shared__ int lbase[8];
  const int wv = threadIdx.x >> 6, lane = threadIdx.x & 63;
  if (threadIdx.x < 8) lcnt[threadIdx.x] = 0;
  __syncthreads();

  for (int i = 0; i < 16; i++) {
    const int tl = wv * 16 + i;
    const int t = blockIdx.x * 64 + tl;
    const float* xr = x + (size_t)t * HDIM + lane * 16;
    float4 xv[4];
#pragma unroll
    for (int j = 0; j < 4; j++) xv[j] = ((const float4*)xr)[j];

    bf16x8 v0, v1;
#pragma unroll
    for (int j = 0; j < 8; j++) v0[j] = (__bf16)((const float*)xv)[j];
#pragma unroll
    for (int j = 0; j < 8; j++) v1[j] = (__bf16)((const float*)xv)[j + 8];
    bf16x8* xbo = (bf16x8*)(xb + (size_t)t * HDIM + lane * 16);
    xbo[0] = v0;
    xbo[1] = v1;

    float acc[8];
#pragma unroll
    for (int e = 0; e < 8; e++) {
      const float4* gp = (const float4*)(gw + e * HDIM + lane * 16);
      float s = 0.f;
#pragma unroll
      for (int j = 0; j < 4; j++) {
        float4 g = gp[j];
        s += xv[j].x * g.x + xv[j].y * g.y + xv[j].z * g.z + xv[j].w * g.w;
      }
      acc[e] = s;
    }
#pragma unroll
    for (int d = 32; d >= 1; d >>= 1) {
#pragma unroll
      for (int e = 0; e < 8; e++) acc[e] += __shfl_xor(acc[e], d, 64);
    }
    if (lane == 0) {
      float mx = acc[0];
#pragma unroll
      for (int e = 1; e < 8; e++) mx = fmaxf(mx, acc[e]);
      float p[8], Z = 0.f;
#pragma unroll
      for (int e = 0; e < 8; e++) {
        p[e] = expf(acc[e] - mx);
        Z += p[e];
      }
#pragma unroll
      for (int e = 0; e < 8; e++) p[e] /= Z;
      int i1 = 0;
#pragma unroll
      for (int e = 1; e < 8; e++)
        if (p[e] > p[i1]) i1 = e;
      int i2 = (i1 == 0) ? 1 : 0;
#pragma unroll
      for (int e = 0; e < 8; e++)
        if (e != i1 && p[e] > p[i2]) i2 = e;
      const float s12 = p[i1] + p[i2] + 1e-20f;
      s_eid[tl][0] = i1;
      s_eid[tl][1] = i2;
      s_wt[tl][0] = p[i1] / s12;
      s_wt[tl][1] = p[i2] / s12;
    }
  }
  __syncthreads();

  if (threadIdx.x < 64) {
    s_rank[threadIdx.x][0] = atomicAdd(&lcnt[s_eid[threadIdx.x][0]], 1);
    s_rank[threadIdx.x][1] = atomicAdd(&lcnt[s_eid[threadIdx.x][1]], 1);
  }
  __syncthreads();
  if (threadIdx.x < 8)
    lbase[threadIdx.x] =
        atomicAdd(&cnt[threadIdx.x * CNT_STRIDE], lcnt[threadIdx.x]);
  __syncthreads();
  if (threadIdx.x < 64) {
    const int t = blockIdx.x * 64 + threadIdx.x;
#pragma unroll
    for (int j = 0; j < 2; j++) {
      const int e = s_eid[threadIdx.x][j];
      const int slot = lbase[e] + s_rank[threadIdx.x][j];
      tok[e * T_TOTAL + slot] = t;
      wtl[e * T_TOTAL + slot] = s_wt[threadIdx.x][j];
      inv[t * 2 + j] = e * T_TOTAL + slot;
    }
  }
}

// ---------------------------------------------------------------------------
// Fused weight prep, single launch. z in [0,9): Wg->Wfu(+0); z in [9,18):
// Wu->Wfu(+16); z in [18,27): Wd->WdT. Scan(cnt)->base folded into block
// (0,0,26) thread 0 (stream-ordered after k_gate).
// ---------------------------------------------------------------------------
__global__ __launch_bounds__(256) void k_wprep(
    const float* __restrict__ Wg, const float* __restrict__ Wu,
    const float* __restrict__ Wd, const float* __restrict__ sWg,
    const float* __restrict__ sWu, const float* __restrict__ sWd,
    __bf16* __restrict__ Wfu, __bf16* __restrict__ WdT,
    const int* __restrict__ cnt, int* __restrict__ base) {
  if (blockIdx.z == 26 && blockIdx.x == 0 && blockIdx.y == 0 &&
      threadIdx.x == 0) {
    int s = 0;
#pragma unroll
    for (int e = 0; e < 8; e++) {
      base[e] = s;
      s += cnt[e * CNT_STRIDE];
    }
  }

  __shared__ float tile[64][65];
  const int z = blockIdx.z;
  const int t = threadIdx.x;

  if (z < 18) {
    // fused-GU transpose: src fp32 [1024 h][512 i] -> Wfu [1024 f][1024 h]
    if (blockIdx.x >= IDIM / 64) return;
    const int b = (z < 9) ? z : z - 9;
    const int u16off = (z < 9) ? 0 : 16;
    const float* w8 = (z < 9) ? Wg : Wu;
    const float* w1 = (z < 9) ? sWg : sWu;
    const float* src = (b < 8) ? (w8 + (size_t)b * HDIM * IDIM) : w1;
    const int c0 = blockIdx.x * 64, r0 = blockIdx.y * 64;  // c=i, r=h

#pragma unroll
    for (int j = 0; j < 4; j++) {
      const int rr = (t >> 4) + j * 16;
      const int cc = (t & 15) * 4;
      const float4 v =
          *(const float4*)(src + (size_t)(r0 + rr) * IDIM + c0 + cc);
      tile[rr][cc] = v.x;
      tile[rr][cc + 1] = v.y;
      tile[rr][cc + 2] = v.z;
      tile[rr][cc + 3] = v.w;
    }
    __syncthreads();

#pragma unroll
    for (int j = 0; j < 2; j++) {
      const int cidx = (t >> 3) + j * 32;  // i-local
      const int rseg = (t & 7) * 8;        // h-local start
      const int ic = c0 + cidx;
      const int f = 2 * (ic & ~15) + (ic & 15) + u16off;
      bf16x8 v;
#pragma unroll
      for (int k = 0; k < 8; k++) v[k] = (__bf16)tile[rseg + k][cidx];
      *(bf16x8*)(Wfu + (size_t)b * 1024 * HDIM + (size_t)f * HDIM + r0 + rseg) =
          v;
    }
  } else {
    // Wd transpose: src fp32 [512 i][1024 h] -> WdT [1024 h][512 i]
    if (blockIdx.y >= IDIM / 64) return;
    const int b = z - 18;
    const float* src = (b < 8) ? (Wd + (size_t)b * IDIM * HDIM) : sWd;
    const int c0 = blockIdx.x * 64, r0 = blockIdx.y * 64;  // c=h, r=i

#pragma unroll
    for (int j = 0; j < 4; j++) {
      const int rr = (t >> 4) + j * 16;
      const int cc = (t & 15) * 4;
      const float4 v =
          *(const float4*)(src + (size_t)(r0 + rr) * HDIM + c0 + cc);
      tile[rr][cc] = v.x;
      tile[rr][cc + 1] = v.y;
      tile[rr][cc + 2] = v.z;
      tile[rr][cc + 3] = v.w;
    }
    __syncthreads();

#pragma unroll
    for (int j = 0; j < 2; j++) {
      const int cidx = (t >> 3) + j * 32;  // h-local
      const int rseg = (t & 7) * 8;        // i-local start
      bf16x8 v;
#pragma unroll
      for (int k = 0; k < 8; k++) v[k] = (__bf16)tile[rseg + k][cidx];
      *(bf16x8*)(WdT + (size_t)b * HDIM * IDIM + (size_t)(c0 + cidx) * IDIM +
                 r0 + rseg) = v;
    }
  }
}

// ---------------------------------------------------------------------------
// Phase A: one GEMM [slots x 128 fused cols], K=H, all 9 experts, one launch.
// N-FASTEST grid (A/B-confirmed -7us: r12 142.7 -> r13 135.6).
// Output rows PACKED: routed base[e]+slot, shared SH_BASE+slot.
// acc[im][2p]=G, acc[im][2p+1]=U for i-col = (n0+wn)/2 + p*16 + l16.
// ---------------------------------------------------------------------------
__global__ __launch_bounds__(256, 2) void k_gu(
    const __bf16* __restrict__ xb, const __bf16* __restrict__ Wfu,
    const int* __restrict__ tok, const float* __restrict__ wtl,
    const int* __restrict__ cnt, const int* __restrict__ base,
    __bf16* __restrict__ inter) {
  const int e = blockIdx.z;
  const bool se = (e == 8);
  const int cnt_e = se ? T_TOTAL : cnt[e * CNT_STRIDE];
  const int m0 = blockIdx.y * 128;
  if (m0 >= cnt_e) return;  // uniform early-exit before any barrier
  const int rowb = se ? SH_BASE : base[e];

  __shared__ __bf16 sA[128][64];
  __shared__ __bf16 sB[128][64];
  const int tid = threadIdx.x, w = tid >> 6, lane = tid & 63;
  const int n0 = blockIdx.x * 128;  // fused-row base (0..896)
  const int quad = lane >> 4, l16 = lane & 15;
  const int wm = (w & 1) * 64, wn = (w >> 1) * 64;

  // staging: 256 thr x 16B = 4KB/shot = 32 rows of 128B; 4 shots per buffer
  const int sr = tid >> 3;                     // row within shot
  const int scs = ((tid & 7) ^ (sr & 7)) * 8;  // swizzled source offset (elems)
  const __bf16* ap[4];
  const __bf16* bp[4];
#pragma unroll
  for (int sh = 0; sh < 4; sh++) {
    int s = m0 + sh * 32 + sr;
    if (s > cnt_e - 1) s = cnt_e - 1;
    const int t = se ? s : tok[e * T_TOTAL + s];
    ap[sh] = xb + (size_t)t * HDIM + scs;
    bp[sh] = Wfu + ((size_t)e * 1024 + n0 + sh * 32 + sr) * HDIM + scs;
  }
  char* const la = (char*)sA + w * 1024;  // +lane*16 implicit in global_load_lds
  char* const lb = (char*)sB + w * 1024;

  f32x4 acc[4][4];
#pragma unroll
  for (int im = 0; im < 4; im++)
#pragma unroll
    for (int in = 0; in < 4; in++) acc[im][in] = {0.f, 0.f, 0.f, 0.f};

  for (int k = 0; k < HDIM; k += 64) {
    __syncthreads();
#pragma unroll
    for (int sh = 0; sh < 4; sh++) {
      load_lds16(ap[sh], la + sh * 4096);
      load_lds16(bp[sh], lb + sh * 4096);
      ap[sh] += 64;
      bp[sh] += 64;
    }
    __syncthreads();
#pragma unroll
    for (int kh = 0; kh < 2; kh++) {
      bf16x8 af[4], bfr[4];
#pragma unroll
      for (int i = 0; i < 4; i++) {
        const int ra = wm + i * 16 + l16;
        af[i] = *(const bf16x8*)((const char*)sA + ra * 128 +
                                 ((kh * 4 + quad) ^ (ra & 7)) * 16);
        const int rb = wn + i * 16 + l16;
        bfr[i] = *(const bf16x8*)((const char*)sB + rb * 128 +
                                  ((kh * 4 + quad) ^ (rb & 7)) * 16);
      }
#pragma unroll
      for (int im = 0; im < 4; im++)
#pragma unroll
        for (int in = 0; in < 4; in++)
          acc[im][in] = mfma_bf16(af[im], bfr[in], acc[im][in]);
    }
  }

  // epilogue: C/D col=lane&15, row=quad*4+r; G/U pairs in even/odd n-frags
#pragma unroll
  for (int im = 0; im < 4; im++) {
#pragma unroll
    for (int r = 0; r < 4; r++) {
      const int slot = m0 + wm + im * 16 + quad * 4 + r;
      if (slot < cnt_e) {
        const float wt = se ? 1.0f : wtl[e * T_TOTAL + slot];
        __bf16* op =
            inter + ((size_t)(rowb + slot)) * IDIM + ((n0 + wn) >> 1) + l16;
#pragma unroll
        for (int p = 0; p < 2; p++) {
          const float g = acc[im][2 * p][r];
          const float u = acc[im][2 * p + 1][r];
          const float v =
              wt * u * 0.5f * g * (1.0f + erff(g * 0.70710678118654752f));
          op[p * 16] = (__bf16)v;
        }
      }
    }
  }
}

// ---------------------------------------------------------------------------
// Phase B routed: per expert e, gathered GEMM over packed inter rows @ Wd[e]
// -> frag-packed f32x4 rows of yb, SEQUENTIAL stores at row=base[e]+slot:
// yb4[(row*16 + nseg)*16 + l16] = cols {nseg*64 + in*16 + l16}.
// M-FASTEST grid (reverted: N-fastest re-read inter x8 across XCDs).
// ---------------------------------------------------------------------------
__global__ __launch_bounds__(256, 2) void k_down_rs(
    const __bf16* __restrict__ inter, const __bf16* __restrict__ WdT,
    const int* __restrict__ cnt, const int* __restrict__ base,
    f32x4* __restrict__ yb4) {
  const int e = blockIdx.z;
  const int cnt_e = cnt[e * CNT_STRIDE];
  const int m0 = blockIdx.x * 128;
  if (m0 >= cnt_e) return;
  const int rowb = base[e];

  __shared__ __bf16 sA[128][64];
  __shared__ __bf16 sB[128][64];
  const int tid = threadIdx.x, w = tid >> 6, lane = tid & 63;
  const int n0 = blockIdx.y * 128;
  const int quad = lane >> 4, l16 = lane & 15;
  const int wm = (w & 1) * 64, wn = (w >> 1) * 64;
  const int nseg = (n0 + wn) >> 6;

  const int sr = tid >> 3;
  const int scs = ((tid & 7) ^ (sr & 7)) * 8;
  const __bf16* ap[4];
  const __bf16* bp[4];
#pragma unroll
  for (int sh = 0; sh < 4; sh++) {
    int s = m0 + sh * 32 + sr;
    if (s > cnt_e - 1) s = cnt_e - 1;
    ap[sh] = inter + (size_t)(rowb + s) * IDIM + scs;
    bp[sh] = WdT + ((size_t)e * HDIM + n0 + sh * 32 + sr) * IDIM + scs;
  }
  char* const la = (char*)sA + w * 1024;
  char* const lb = (char*)sB + w * 1024;

  f32x4 acc[4][4];
#pragma unroll
  for (int im = 0; im < 4; im++)
#pragma unroll
    for (int in = 0; in < 4; in++) acc[im][in] = {0.f, 0.f, 0.f, 0.f};

  for (int k = 0; k < IDIM; k += 64) {
    __syncthreads();
#pragma unroll
    for (int sh = 0; sh < 4; sh++) {
      load_lds16(ap[sh], la + sh * 4096);
      load_lds16(bp[sh], lb + sh * 4096);
      ap[sh] += 64;
      bp[sh] += 64;
    }
    __syncthreads();
#pragma unroll
    for (int kh = 0; kh < 2; kh++) {
      bf16x8 af[4], bfr[4];
#pragma unroll
      for (int i = 0; i < 4; i++) {
        const int ra = wm + i * 16 + l16;
        af[i] = *(const bf16x8*)((const char*)sA + ra * 128 +
                                 ((kh * 4 + quad) ^ (ra & 7)) * 16);
        const int rb = wn + i * 16 + l16;
        bfr[i] = *(const bf16x8*)((const char*)sB + rb * 128 +
                                  ((kh * 4 + quad) ^ (rb & 7)) * 16);
      }
#pragma unroll
      for (int im = 0; im < 4; im++)
#pragma unroll
        for (int in = 0; in < 4; in++)
          acc[im][in] = mfma_bf16(af[im], bfr[in], acc[im][in]);
    }
  }

#pragma unroll
  for (int im = 0; im < 4; im++) {
#pragma unroll
    for (int r = 0; r < 4; r++) {
      const int slot = m0 + wm + im * 16 + quad * 4 + r;
      if (slot < cnt_e) {
        const size_t row = (size_t)(rowb + slot);
        f32x4 v = {acc[im][0][r], acc[im][1][r], acc[im][2][r], acc[im][3][r]};
        yb4[(row * 16 + nseg) * 16 + l16] = v;
      }
    }
  }
}

// ---------------------------------------------------------------------------
// Phase B shared + combine: out[t] = inter[shared] @ sWd + yb[r1(t)] + yb[r2(t)].
// Routed rows gathered from frag-packed yb4 via inv[] in the GEMM epilogue.
// M-FASTEST grid (reverted).
// ---------------------------------------------------------------------------
__global__ __launch_bounds__(256, 2) void k_down_sc(
    const __bf16* __restrict__ iA, const __bf16* __restrict__ wB,
    const f32x4* __restrict__ yb4, const int* __restrict__ inv,
    const int* __restrict__ base, float* __restrict__ out) {
  __shared__ __bf16 sA[128][64];
  __shared__ __bf16 sB[128][64];
  const int tid = threadIdx.x, w = tid >> 6, lane = tid & 63;
  const int m0 = blockIdx.x * 128, n0 = blockIdx.y * 128;
  const int quad = lane >> 4, l16 = lane & 15;
  const int wm = (w & 1) * 64, wn = (w >> 1) * 64;
  const int nseg = (n0 + wn) >> 6;

  const int sr = tid >> 3;
  const int scs = ((tid & 7) ^ (sr & 7)) * 8;
  const __bf16* ap[4];
  const __bf16* bp[4];
#pragma unroll
  for (int sh = 0; sh < 4; sh++) {
    ap[sh] = iA + (size_t)(m0 + sh * 32 + sr) * IDIM + scs;
    bp[sh] = wB + (size_t)(n0 + sh * 32 + sr) * IDIM + scs;
  }
  char* const la = (char*)sA + w * 1024;
  char* const lb = (char*)sB + w * 1024;

  f32x4 acc[4][4];
#pragma unroll
  for (int im = 0; im < 4; im++)
#pragma unroll
    for (int in = 0; in < 4; in++) acc[im][in] = {0.f, 0.f, 0.f, 0.f};

  for (int k = 0; k < IDIM; k += 64) {
    __syncthreads();
#pragma unroll
    for (int sh = 0; sh < 4; sh++) {
      load_lds16(ap[sh], la + sh * 4096);
      load_lds16(bp[sh], lb + sh * 4096);
      ap[sh] += 64;
      bp[sh] += 64;
    }
    __syncthreads();
#pragma unroll
    for (int kh = 0; kh < 2; kh++) {
      bf16x8 af[4], bfr[4];
#pragma unroll
      for (int i = 0; i < 4; i++) {
        const int ra = wm + i * 16 + l16;
        af[i] = *(const bf16x8*)((const char*)sA + ra * 128 +
                                 ((kh * 4 + quad) ^ (ra & 7)) * 16);
        const int rb = wn + i * 16 + l16;
        bfr[i] = *(const bf16x8*)((const char*)sB + rb * 128 +
                                  ((kh * 4 + quad) ^ (rb & 7)) * 16);
      }
#pragma unroll
      for (int im = 0; im < 4; im++)
#pragma unroll
        for (int in = 0; in < 4; in++)
          acc[im][in] = mfma_bf16(af[im], bfr[in], acc[im][in]);
    }
  }

#pragma unroll
  for (int im = 0; im < 4; im++) {
#pragma unroll
    for (int r = 0; r < 4; r++) {
      const int t = m0 + wm + im * 16 + quad * 4 + r;
      const int v1 = inv[2 * t], v2 = inv[2 * t + 1];
      const size_t r1 = base[v1 >> 14] + (v1 & (T_TOTAL - 1));
      const size_t r2 = base[v2 >> 14] + (v2 & (T_TOTAL - 1));
      const f32x4 y1 = yb4[(r1 * 16 + nseg) * 16 + l16];
      const f32x4 y2 = yb4[(r2 * 16 + nseg) * 16 + l16];
      float* op = out + (size_t)t * HDIM + n0 + wn + l16;
#pragma unroll
      for (int in = 0; in < 4; in++)
        op[in * 16] = acc[im][in][r] + y1[in] + y2[in];
    }
  }
}

// ---------------------------------------------------------------------------
// Fallback path (ws too small for yb): shared GEMM plain stores, then routed
// atomic scatter-add on packed inter.
// ---------------------------------------------------------------------------
__global__ __launch_bounds__(256, 2) void k_down_s(const __bf16* __restrict__ iA,
                                                   const __bf16* __restrict__ wB,
                                                   float* __restrict__ out) {
  __shared__ __bf16 sA[128][64];
  __shared__ __bf16 sB[128][64];
  const int tid = threadIdx.x, w = tid >> 6, lane = tid & 63;
  const int m0 = blockIdx.x * 128, n0 = blockIdx.y * 128;
  const int quad = lane >> 4, l16 = lane & 15;
  const int wm = (w & 1) * 64, wn = (w >> 1) * 64;

  const int sr = tid >> 3;
  const int scs = ((tid & 7) ^ (sr & 7)) * 8;
  const __bf16* ap[4];
  const __bf16* bp[4];
#pragma unroll
  for (int sh = 0; sh < 4; sh++) {
    ap[sh] = iA + (size_t)(m0 + sh * 32 + sr) * IDIM + scs;
    bp[sh] = wB + (size_t)(n0 + sh * 32 + sr) * IDIM + scs;
  }
  char* const la = (char*)sA + w * 1024;
  char* const lb = (char*)sB + w * 1024;

  f32x4 acc[4][4];
#pragma unroll
  for (int im = 0; im < 4; im++)
#pragma unroll
    for (int in = 0; in < 4; in++) acc[im][in] = {0.f, 0.f, 0.f, 0.f};

  for (int k = 0; k < IDIM; k += 64) {
    __syncthreads();
#pragma unroll
    for (int sh = 0; sh < 4; sh++) {
      load_lds16(ap[sh], la + sh * 4096);
      load_lds16(bp[sh], lb + sh * 4096);
      ap[sh] += 64;
      bp[sh] += 64;
    }
    __syncthreads();
#pragma unroll
    for (int kh = 0; kh < 2; kh++) {
      bf16x8 af[4], bfr[4];
#pragma unroll
      for (int i = 0; i < 4; i++) {
        const int ra = wm + i * 16 + l16;
        af[i] = *(const bf16x8*)((const char*)sA + ra * 128 +
                                 ((kh * 4 + quad) ^ (ra & 7)) * 16);
        const int rb = wn + i * 16 + l16;
        bfr[i] = *(const bf16x8*)((const char*)sB + rb * 128 +
                                  ((kh * 4 + quad) ^ (rb & 7)) * 16);
      }
#pragma unroll
      for (int im = 0; im < 4; im++)
#pragma unroll
        for (int in = 0; in < 4; in++)
          acc[im][in] = mfma_bf16(af[im], bfr[in], acc[im][in]);
    }
  }

#pragma unroll
  for (int im = 0; im < 4; im++) {
#pragma unroll
    for (int r = 0; r < 4; r++) {
      const int t = m0 + wm + im * 16 + quad * 4 + r;
#pragma unroll
      for (int in = 0; in < 4; in++)
        out[(size_t)t * HDIM + n0 + wn + in * 16 + l16] = acc[im][in][r];
    }
  }
}

__global__ __launch_bounds__(256, 2) void k_down_r(
    const __bf16* __restrict__ inter, const __bf16* __restrict__ WdT,
    const int* __restrict__ tok, const int* __restrict__ cnt,
    const int* __restrict__ base, float* __restrict__ out) {
  const int e = blockIdx.z;
  const int cnt_e = cnt[e * CNT_STRIDE];
  const int m0 = blockIdx.x * 128;
  if (m0 >= cnt_e) return;
  const int rowb = base[e];

  __shared__ __bf16 sA[128][64];
  __shared__ __bf16 sB[128][64];
  const int tid = threadIdx.x, w = tid >> 6, lane = tid & 63;
  const int n0 = blockIdx.y * 128;
  const int quad = lane >> 4, l16 = lane & 15;
  const int wm = (w & 1) * 64, wn = (w >> 1) * 64;

  const int sr = tid >> 3;
  const int scs = ((tid & 7) ^ (sr & 7)) * 8;
  const __bf16* ap[4];
  const __bf16* bp[4];
#pragma unroll
  for (int sh = 0; sh < 4; sh++) {
    int s = m0 + sh * 32 + sr;
    if (s > cnt_e - 1) s = cnt_e - 1;
    ap[sh] = inter + (size_t)(rowb + s) * IDIM + scs;
    bp[sh] = WdT + ((size_t)e * HDIM + n0 + sh * 32 + sr) * IDIM + scs;
  }
  char* const la = (char*)sA + w * 1024;
  char* const lb = (char*)sB + w * 1024;

  f32x4 acc[4][4];
#pragma unroll
  for (int im = 0; im < 4; im++)
#pragma unroll
    for (int in = 0; in < 4; in++) acc[im][in] = {0.f, 0.f, 0.f, 0.f};

  for (int k = 0; k < IDIM; k += 64) {
    __syncthreads();
#pragma unroll
    for (int sh = 0; sh < 4; sh++) {
      load_lds16(ap[sh], la + sh * 4096);
      load_lds16(bp[sh], lb + sh * 4096);
      ap[sh] += 64;
      bp[sh] += 64;
    }
    __syncthreads();
#pragma unroll
    for (int kh = 0; kh < 2; kh++) {
      bf16x8 af[4], bfr[4];
#pragma unroll
      for (int i = 0; i < 4; i++) {
        const int ra = wm + i * 16 + l16;
        af[i] = *(const bf16x8*)((const char*)sA + ra * 128 +
                                 ((kh * 4 + quad) ^ (ra & 7)) * 16);
        const int rb = wn + i * 16 + l16;
        bfr[i] = *(const bf16x8*)((const char*)sB + rb * 128 +
                                  ((kh * 4 + quad) ^ (rb & 7)) * 16);
      }
#pragma unroll
      for (int im = 0; im < 4; im++)
#pragma unroll
        for (int in = 0; in < 4; in++)
          acc[im][in] = mfma_bf16(af[im], bfr[in], acc[im][in]);
    }
  }

#pragma unroll
  for (int im = 0; im < 4; im++) {
#pragma unroll
    for (int r = 0; r < 4; r++) {
      const int slot = m0 + wm + im * 16 + quad * 4 + r;
      if (slot < cnt_e) {
        const int t = tok[e * T_TOTAL + slot];
#pragma unroll
        for (int in = 0; in < 4; in++)
          atomicAdd(&out[(size_t)t * HDIM + n0 + wn + in * 16 + l16],
                    acc[im][in][r]);
      }
    }
  }
}

// ---------------------------------------------------------------------------
extern "C" void kernel_launch(void* const* d_in, const int* in_sizes, int n_in,
                              void* d_out, int out_size, void* d_ws,
                              size_t ws_size, hipStream_t stream) {
  const float* x = (const float*)d_in[0];
  const float* gw = (const float*)d_in[1];
  const float* Wg = (const float*)d_in[2];
  const float* Wu = (const float*)d_in[3];
  const float* Wd = (const float*)d_in[4];
  const float* sWg = (const float*)d_in[5];
  const float* sWu = (const float*)d_in[6];
  const float* sWd = (const float*)d_in[7];
  float* out = (float*)d_out;

  char* ws = (char*)d_ws;
  size_t off = 0;
  auto alloc = [&](size_t n) {
    char* p = ws + off;
    off += (n + 255) & ~(size_t)255;
    return p;
  };
  // --- persistent through phase B ---
  __bf16* WdT = (__bf16*)alloc((size_t)NE * HDIM * IDIM * 2);       // 9.4 MB
  int* tok = (int*)alloc((size_t)8 * T_TOTAL * 4);                  // 512 KB
  float* wtl = (float*)alloc((size_t)8 * T_TOTAL * 4);              // 512 KB
  int* cnt = (int*)alloc(8 * CNT_STRIDE * 4);
  int* inv = (int*)alloc((size_t)T_TOTAL * 2 * 4);                  // 128 KB
  int* base = (int*)alloc(16 * 4);
  __bf16* inter = (__bf16*)alloc((size_t)(3 * T_TOTAL) * IDIM * 2); // 50.3 MB
  const size_t off_persist = off;                                   // ~60.9 MB
  // --- dead after k_gu (yb aliases this region) ---
  __bf16* xb = (__bf16*)alloc((size_t)T_TOTAL * HDIM * 2);          // 33.5 MB
  __bf16* Wfu = (__bf16*)alloc((size_t)NE * 1024 * HDIM * 2);       // 18.9 MB

  // Frag-packed routed down-proj output: 2T rows x H fp32 = 134 MB, aliased
  // over xb+Wfu (stream order: k_down_rs runs after k_gu's last read).
  const size_t yb_bytes = (size_t)2 * T_TOTAL * HDIM * 4;
  const bool store_path = (off_persist + yb_bytes) <= ws_size;  // needs 195 MB
  f32x4* yb4 = (f32x4*)(ws + off_persist);

  hipMemsetAsync(cnt, 0, 8 * CNT_STRIDE * 4, stream);

  k_gate<<<dim3(T_TOTAL / 64), dim3(256), 0, stream>>>(x, gw, xb, tok, wtl,
                                                       cnt, inv);
  // All weight prep (G-fuse, U-fuse, Wd transpose) + scan in one launch.
  k_wprep<<<dim3(16, 16, 27), dim3(256), 0, stream>>>(Wg, Wu, Wd, sWg, sWu,
                                                      sWd, Wfu, WdT, cnt, base);

  // Phase A: fused GU into packed inter; N-fastest grid (kept).
  k_gu<<<dim3(1024 / 128, T_TOTAL / 128, NE), dim3(256), 0, stream>>>(
      xb, Wfu, tok, wtl, cnt, base, inter);

  if (store_path) {
    // routed experts -> frag-packed yb4 (sequential stores), then shared +
    // inv-gathered combine. M-fastest grid (reverted).
    k_down_rs<<<dim3(T_TOTAL / 128, HDIM / 128, 8), dim3(256), 0, stream>>>(
        inter, WdT, cnt, base, yb4);
    k_down_sc<<<dim3(T_TOTAL / 128, HDIM / 128), dim3(256), 0, stream>>>(
        inter + (size_t)SH_BASE * IDIM, WdT + (size_t)8 * HDIM * IDIM, yb4, inv,
        base, out);
  } else {
    // fallback: shared GEMM stores, routed atomic scatter-add
    k_down_s<<<dim3(T_TOTAL / 128, HDIM / 128), dim3(256), 0, stream>>>(
        inter + (size_t)SH_BASE * IDIM, WdT + (size_t)8 * HDIM * IDIM, out);
    k_down_r<<<dim3(T_TOTAL / 128, HDIM / 128, 8), dim3(256), 0, stream>>>(
        inter, WdT, tok, cnt, base, out);
  }
}

// Round 11
// 419.276 us; speedup vs baseline: 1.0732x; 1.0041x over previous
//
#include <hip/hip_runtime.h>
#include <hip/hip_bf16.h>
#include <math.h>

// ---------------------------------------------------------------------------
// DeepseekV2 MoE: T=16384 tokens, H=1024, E=8 routed (top-2) + 1 shared, I=512
// Round 15: yb precision change (single variable vs r14).
//  - yb: fp32 f32x4 -> PACKED bf16x4 fragments (same frag layout, half bytes).
//    rs write 134->67 MB; sc read 134->67 MB (now fully L3-resident).
//    Final sum out = shared + y1 + y2 still fp32; only y rounds once to bf16.
//  - Everything else identical to r14 (421us): k_gu merged N-fastest grid,
//    rs/sc M-fastest, r10 frag-packed layout, wprep+scan fusion, 5 launches.
// ---------------------------------------------------------------------------

#define T_TOTAL 16384
#define HDIM 1024
#define IDIM 512
#define NE 9  // 8 routed + 1 shared (expert index 8)
#define CNT_STRIDE 16
#define SH_BASE 32768  // packed-inter row where shared expert starts

typedef __bf16 bf16x8 __attribute__((ext_vector_type(8)));
typedef __bf16 bf16x4 __attribute__((ext_vector_type(4)));
typedef float f32x4 __attribute__((ext_vector_type(4)));

typedef __attribute__((address_space(1))) void gvoid_t;
typedef __attribute__((address_space(3))) void lvoid_t;

__device__ __forceinline__ void load_lds16(const void* g, void* l) {
  // 16B/lane; LDS dest = wave-uniform base + lane*16 (global src may scatter)
  __builtin_amdgcn_global_load_lds((const gvoid_t*)g, (lvoid_t*)l, 16, 0, 0);
}

__device__ __forceinline__ f32x4 mfma_bf16(bf16x8 a, bf16x8 b, f32x4 c) {
  return __builtin_amdgcn_mfma_f32_16x16x32_bf16(a, b, c, 0, 0, 0);
}

// ---------------------------------------------------------------------------
// Gate: block-aggregated slot assignment. Writes inv[t*2+j] = e*16384+slot
// (T_TOTAL = 2^14 -> decode e = v>>14, slot = v&16383).
// ---------------------------------------------------------------------------
__global__ __launch_bounds__(256) void k_gate(const float* __restrict__ x,
                                              const float* __restrict__ gw,
                                              __bf16* __restrict__ xb,
                                              int* __restrict__ tok,
                                              float* __restrict__ wtl,
                                              int* __restrict__ cnt,
                                              int* __restrict__ inv) {
  __shared__ int s_eid[64][2];
  __shared__ float s_wt[64][2];
  __shared__ int s_rank[64][2];
  __shared__ int lcnt[8];
  __shared__ int lbase[8];
  const int wv = threadIdx.x >> 6, lane = threadIdx.x & 63;
  if (threadIdx.x < 8) lcnt[threadIdx.x] = 0;
  __syncthreads();

  for (int i = 0; i < 16; i++) {
    const int tl = wv * 16 + i;
    const int t = blockIdx.x * 64 + tl;
    const float* xr = x + (size_t)t * HDIM + lane * 16;
    float4 xv[4];
#pragma unroll
    for (int j = 0; j < 4; j++) xv[j] = ((const float4*)xr)[j];

    bf16x8 v0, v1;
#pragma unroll
    for (int j = 0; j < 8; j++) v0[j] = (__bf16)((const float*)xv)[j];
#pragma unroll
    for (int j = 0; j < 8; j++) v1[j] = (__bf16)((const float*)xv)[j + 8];
    bf16x8* xbo = (bf16x8*)(xb + (size_t)t * HDIM + lane * 16);
    xbo[0] = v0;
    xbo[1] = v1;

    float acc[8];
#pragma unroll
    for (int e = 0; e < 8; e++) {
      const float4* gp = (const float4*)(gw + e * HDIM + lane * 16);
      float s = 0.f;
#pragma unroll
      for (int j = 0; j < 4; j++) {
        float4 g = gp[j];
        s += xv[j].x * g.x + xv[j].y * g.y + xv[j].z * g.z + xv[j].w * g.w;
      }
      acc[e] = s;
    }
#pragma unroll
    for (int d = 32; d >= 1; d >>= 1) {
#pragma unroll
      for (int e = 0; e < 8; e++) acc[e] += __shfl_xor(acc[e], d, 64);
    }
    if (lane == 0) {
      float mx = acc[0];
#pragma unroll
      for (int e = 1; e < 8; e++) mx = fmaxf(mx, acc[e]);
      float p[8], Z = 0.f;
#pragma unroll
      for (int e = 0; e < 8; e++) {
        p[e] = expf(acc[e] - mx);
        Z += p[e];
      }
#pragma unroll
      for (int e = 0; e < 8; e++) p[e] /= Z;
      int i1 = 0;
#pragma unroll
      for (int e = 1; e < 8; e++)
        if (p[e] > p[i1]) i1 = e;
      int i2 = (i1 == 0) ? 1 : 0;
#pragma unroll
      for (int e = 0; e < 8; e++)
        if (e != i1 && p[e] > p[i2]) i2 = e;
      const float s12 = p[i1] + p[i2] + 1e-20f;
      s_eid[tl][0] = i1;
      s_eid[tl][1] = i2;
      s_wt[tl][0] = p[i1] / s12;
      s_wt[tl][1] = p[i2] / s12;
    }
  }
  __syncthreads();

  if (threadIdx.x < 64) {
    s_rank[threadIdx.x][0] = atomicAdd(&lcnt[s_eid[threadIdx.x][0]], 1);
    s_rank[threadIdx.x][1] = atomicAdd(&lcnt[s_eid[threadIdx.x][1]], 1);
  }
  __syncthreads();
  if (threadIdx.x < 8)
    lbase[threadIdx.x] =
        atomicAdd(&cnt[threadIdx.x * CNT_STRIDE], lcnt[threadIdx.x]);
  __syncthreads();
  if (threadIdx.x < 64) {
    const int t = blockIdx.x * 64 + threadIdx.x;
#pragma unroll
    for (int j = 0; j < 2; j++) {
      const int e = s_eid[threadIdx.x][j];
      const int slot = lbase[e] + s_rank[threadIdx.x][j];
      tok[e * T_TOTAL + slot] = t;
      wtl[e * T_TOTAL + slot] = s_wt[threadIdx.x][j];
      inv[t * 2 + j] = e * T_TOTAL + slot;
    }
  }
}

// ---------------------------------------------------------------------------
// Fused weight prep, single launch. z in [0,9): Wg->Wfu(+0); z in [9,18):
// Wu->Wfu(+16); z in [18,27): Wd->WdT. Scan(cnt)->base folded into block
// (0,0,26) thread 0 (stream-ordered after k_gate).
// ---------------------------------------------------------------------------
__global__ __launch_bounds__(256) void k_wprep(
    const float* __restrict__ Wg, const float* __restrict__ Wu,
    const float* __restrict__ Wd, const float* __restrict__ sWg,
    const float* __restrict__ sWu, const float* __restrict__ sWd,
    __bf16* __restrict__ Wfu, __bf16* __restrict__ WdT,
    const int* __restrict__ cnt, int* __restrict__ base) {
  if (blockIdx.z == 26 && blockIdx.x == 0 && blockIdx.y == 0 &&
      threadIdx.x == 0) {
    int s = 0;
#pragma unroll
    for (int e = 0; e < 8; e++) {
      base[e] = s;
      s += cnt[e * CNT_STRIDE];
    }
  }

  __shared__ float tile[64][65];
  const int z = blockIdx.z;
  const int t = threadIdx.x;

  if (z < 18) {
    // fused-GU transpose: src fp32 [1024 h][512 i] -> Wfu [1024 f][1024 h]
    if (blockIdx.x >= IDIM / 64) return;
    const int b = (z < 9) ? z : z - 9;
    const int u16off = (z < 9) ? 0 : 16;
    const float* w8 = (z < 9) ? Wg : Wu;
    const float* w1 = (z < 9) ? sWg : sWu;
    const float* src = (b < 8) ? (w8 + (size_t)b * HDIM * IDIM) : w1;
    const int c0 = blockIdx.x * 64, r0 = blockIdx.y * 64;  // c=i, r=h

#pragma unroll
    for (int j = 0; j < 4; j++) {
      const int rr = (t >> 4) + j * 16;
      const int cc = (t & 15) * 4;
      const float4 v =
          *(const float4*)(src + (size_t)(r0 + rr) * IDIM + c0 + cc);
      tile[rr][cc] = v.x;
      tile[rr][cc + 1] = v.y;
      tile[rr][cc + 2] = v.z;
      tile[rr][cc + 3] = v.w;
    }
    __syncthreads();

#pragma unroll
    for (int j = 0; j < 2; j++) {
      const int cidx = (t >> 3) + j * 32;  // i-local
      const int rseg = (t & 7) * 8;        // h-local start
      const int ic = c0 + cidx;
      const int f = 2 * (ic & ~15) + (ic & 15) + u16off;
      bf16x8 v;
#pragma unroll
      for (int k = 0; k < 8; k++) v[k] = (__bf16)tile[rseg + k][cidx];
      *(bf16x8*)(Wfu + (size_t)b * 1024 * HDIM + (size_t)f * HDIM + r0 + rseg) =
          v;
    }
  } else {
    // Wd transpose: src fp32 [512 i][1024 h] -> WdT [1024 h][512 i]
    if (blockIdx.y >= IDIM / 64) return;
    const int b = z - 18;
    const float* src = (b < 8) ? (Wd + (size_t)b * IDIM * HDIM) : sWd;
    const int c0 = blockIdx.x * 64, r0 = blockIdx.y * 64;  // c=h, r=i

#pragma unroll
    for (int j = 0; j < 4; j++) {
      const int rr = (t >> 4) + j * 16;
      const int cc = (t & 15) * 4;
      const float4 v =
          *(const float4*)(src + (size_t)(r0 + rr) * HDIM + c0 + cc);
      tile[rr][cc] = v.x;
      tile[rr][cc + 1] = v.y;
      tile[rr][cc + 2] = v.z;
      tile[rr][cc + 3] = v.w;
    }
    __syncthreads();

#pragma unroll
    for (int j = 0; j < 2; j++) {
      const int cidx = (t >> 3) + j * 32;  // h-local
      const int rseg = (t & 7) * 8;        // i-local start
      bf16x8 v;
#pragma unroll
      for (int k = 0; k < 8; k++) v[k] = (__bf16)tile[rseg + k][cidx];
      *(bf16x8*)(WdT + (size_t)b * HDIM * IDIM + (size_t)(c0 + cidx) * IDIM +
                 r0 + rseg) = v;
    }
  }
}

// ---------------------------------------------------------------------------
// Phase A: one GEMM [slots x 128 fused cols], K=H, all 9 experts, one launch.
// N-FASTEST grid (A/B-confirmed -7us). Output rows PACKED.
// acc[im][2p]=G, acc[im][2p+1]=U for i-col = (n0+wn)/2 + p*16 + l16.
// ---------------------------------------------------------------------------
__global__ __launch_bounds__(256, 2) void k_gu(
    const __bf16* __restrict__ xb, const __bf16* __restrict__ Wfu,
    const int* __restrict__ tok, const float* __restrict__ wtl,
    const int* __restrict__ cnt, const int* __restrict__ base,
    __bf16* __restrict__ inter) {
  const int e = blockIdx.z;
  const bool se = (e == 8);
  const int cnt_e = se ? T_TOTAL : cnt[e * CNT_STRIDE];
  const int m0 = blockIdx.y * 128;
  if (m0 >= cnt_e) return;  // uniform early-exit before any barrier
  const int rowb = se ? SH_BASE : base[e];

  __shared__ __bf16 sA[128][64];
  __shared__ __bf16 sB[128][64];
  const int tid = threadIdx.x, w = tid >> 6, lane = tid & 63;
  const int n0 = blockIdx.x * 128;  // fused-row base (0..896)
  const int quad = lane >> 4, l16 = lane & 15;
  const int wm = (w & 1) * 64, wn = (w >> 1) * 64;

  // staging: 256 thr x 16B = 4KB/shot = 32 rows of 128B; 4 shots per buffer
  const int sr = tid >> 3;                     // row within shot
  const int scs = ((tid & 7) ^ (sr & 7)) * 8;  // swizzled source offset (elems)
  const __bf16* ap[4];
  const __bf16* bp[4];
#pragma unroll
  for (int sh = 0; sh < 4; sh++) {
    int s = m0 + sh * 32 + sr;
    if (s > cnt_e - 1) s = cnt_e - 1;
    const int t = se ? s : tok[e * T_TOTAL + s];
    ap[sh] = xb + (size_t)t * HDIM + scs;
    bp[sh] = Wfu + ((size_t)e * 1024 + n0 + sh * 32 + sr) * HDIM + scs;
  }
  char* const la = (char*)sA + w * 1024;  // +lane*16 implicit in global_load_lds
  char* const lb = (char*)sB + w * 1024;

  f32x4 acc[4][4];
#pragma unroll
  for (int im = 0; im < 4; im++)
#pragma unroll
    for (int in = 0; in < 4; in++) acc[im][in] = {0.f, 0.f, 0.f, 0.f};

  for (int k = 0; k < HDIM; k += 64) {
    __syncthreads();
#pragma unroll
    for (int sh = 0; sh < 4; sh++) {
      load_lds16(ap[sh], la + sh * 4096);
      load_lds16(bp[sh], lb + sh * 4096);
      ap[sh] += 64;
      bp[sh] += 64;
    }
    __syncthreads();
#pragma unroll
    for (int kh = 0; kh < 2; kh++) {
      bf16x8 af[4], bfr[4];
#pragma unroll
      for (int i = 0; i < 4; i++) {
        const int ra = wm + i * 16 + l16;
        af[i] = *(const bf16x8*)((const char*)sA + ra * 128 +
                                 ((kh * 4 + quad) ^ (ra & 7)) * 16);
        const int rb = wn + i * 16 + l16;
        bfr[i] = *(const bf16x8*)((const char*)sB + rb * 128 +
                                  ((kh * 4 + quad) ^ (rb & 7)) * 16);
      }
#pragma unroll
      for (int im = 0; im < 4; im++)
#pragma unroll
        for (int in = 0; in < 4; in++)
          acc[im][in] = mfma_bf16(af[im], bfr[in], acc[im][in]);
    }
  }

  // epilogue: C/D col=lane&15, row=quad*4+r; G/U pairs in even/odd n-frags
#pragma unroll
  for (int im = 0; im < 4; im++) {
#pragma unroll
    for (int r = 0; r < 4; r++) {
      const int slot = m0 + wm + im * 16 + quad * 4 + r;
      if (slot < cnt_e) {
        const float wt = se ? 1.0f : wtl[e * T_TOTAL + slot];
        __bf16* op =
            inter + ((size_t)(rowb + slot)) * IDIM + ((n0 + wn) >> 1) + l16;
#pragma unroll
        for (int p = 0; p < 2; p++) {
          const float g = acc[im][2 * p][r];
          const float u = acc[im][2 * p + 1][r];
          const float v =
              wt * u * 0.5f * g * (1.0f + erff(g * 0.70710678118654752f));
          op[p * 16] = (__bf16)v;
        }
      }
    }
  }
}

// ---------------------------------------------------------------------------
// Phase B routed: per expert e, gathered GEMM over packed inter rows @ Wd[e]
// -> frag-packed BF16x4 rows of yb, SEQUENTIAL stores at row=base[e]+slot:
// yb4[(row*16 + nseg)*16 + l16] = cols {nseg*64 + in*16 + l16}. M-FASTEST grid.
// ---------------------------------------------------------------------------
__global__ __launch_bounds__(256, 2) void k_down_rs(
    const __bf16* __restrict__ inter, const __bf16* __restrict__ WdT,
    const int* __restrict__ cnt, const int* __restrict__ base,
    bf16x4* __restrict__ yb4) {
  const int e = blockIdx.z;
  const int cnt_e = cnt[e * CNT_STRIDE];
  const int m0 = blockIdx.x * 128;
  if (m0 >= cnt_e) return;
  const int rowb = base[e];

  __shared__ __bf16 sA[128][64];
  __shared__ __bf16 sB[128][64];
  const int tid = threadIdx.x, w = tid >> 6, lane = tid & 63;
  const int n0 = blockIdx.y * 128;
  const int quad = lane >> 4, l16 = lane & 15;
  const int wm = (w & 1) * 64, wn = (w >> 1) * 64;
  const int nseg = (n0 + wn) >> 6;

  const int sr = tid >> 3;
  const int scs = ((tid & 7) ^ (sr & 7)) * 8;
  const __bf16* ap[4];
  const __bf16* bp[4];
#pragma unroll
  for (int sh = 0; sh < 4; sh++) {
    int s = m0 + sh * 32 + sr;
    if (s > cnt_e - 1) s = cnt_e - 1;
    ap[sh] = inter + (size_t)(rowb + s) * IDIM + scs;
    bp[sh] = WdT + ((size_t)e * HDIM + n0 + sh * 32 + sr) * IDIM + scs;
  }
  char* const la = (char*)sA + w * 1024;
  char* const lb = (char*)sB + w * 1024;

  f32x4 acc[4][4];
#pragma unroll
  for (int im = 0; im < 4; im++)
#pragma unroll
    for (int in = 0; in < 4; in++) acc[im][in] = {0.f, 0.f, 0.f, 0.f};

  for (int k = 0; k < IDIM; k += 64) {
    __syncthreads();
#pragma unroll
    for (int sh = 0; sh < 4; sh++) {
      load_lds16(ap[sh], la + sh * 4096);
      load_lds16(bp[sh], lb + sh * 4096);
      ap[sh] += 64;
      bp[sh] += 64;
    }
    __syncthreads();
#pragma unroll
    for (int kh = 0; kh < 2; kh++) {
      bf16x8 af[4], bfr[4];
#pragma unroll
      for (int i = 0; i < 4; i++) {
        const int ra = wm + i * 16 + l16;
        af[i] = *(const bf16x8*)((const char*)sA + ra * 128 +
                                 ((kh * 4 + quad) ^ (ra & 7)) * 16);
        const int rb = wn + i * 16 + l16;
        bfr[i] = *(const bf16x8*)((const char*)sB + rb * 128 +
                                  ((kh * 4 + quad) ^ (rb & 7)) * 16);
      }
#pragma unroll
      for (int im = 0; im < 4; im++)
#pragma unroll
        for (int in = 0; in < 4; in++)
          acc[im][in] = mfma_bf16(af[im], bfr[in], acc[im][in]);
    }
  }

#pragma unroll
  for (int im = 0; im < 4; im++) {
#pragma unroll
    for (int r = 0; r < 4; r++) {
      const int slot = m0 + wm + im * 16 + quad * 4 + r;
      if (slot < cnt_e) {
        const size_t row = (size_t)(rowb + slot);
        bf16x4 v;
#pragma unroll
        for (int in = 0; in < 4; in++) v[in] = (__bf16)acc[im][in][r];
        yb4[(row * 16 + nseg) * 16 + l16] = v;
      }
    }
  }
}

// ---------------------------------------------------------------------------
// Phase B shared + combine: out[t] = inter[shared] @ sWd + yb[r1(t)] + yb[r2(t)].
// Routed rows gathered from frag-packed bf16 yb4 via inv[]; fp32 final sum.
// M-FASTEST grid.
// ---------------------------------------------------------------------------
__global__ __launch_bounds__(256, 2) void k_down_sc(
    const __bf16* __restrict__ iA, const __bf16* __restrict__ wB,
    const bf16x4* __restrict__ yb4, const int* __restrict__ inv,
    const int* __restrict__ base, float* __restrict__ out) {
  __shared__ __bf16 sA[128][64];
  __shared__ __bf16 sB[128][64];
  const int tid = threadIdx.x, w = tid >> 6, lane = tid & 63;
  const int m0 = blockIdx.x * 128, n0 = blockIdx.y * 128;
  const int quad = lane >> 4, l16 = lane & 15;
  const int wm = (w & 1) * 64, wn = (w >> 1) * 64;
  const int nseg = (n0 + wn) >> 6;

  const int sr = tid >> 3;
  const int scs = ((tid & 7) ^ (sr & 7)) * 8;
  const __bf16* ap[4];
  const __bf16* bp[4];
#pragma unroll
  for (int sh = 0; sh < 4; sh++) {
    ap[sh] = iA + (size_t)(m0 + sh * 32 + sr) * IDIM + scs;
    bp[sh] = wB + (size_t)(n0 + sh * 32 + sr) * IDIM + scs;
  }
  char* const la = (char*)sA + w * 1024;
  char* const lb = (char*)sB + w * 1024;

  f32x4 acc[4][4];
#pragma unroll
  for (int im = 0; im < 4; im++)
#pragma unroll
    for (int in = 0; in < 4; in++) acc[im][in] = {0.f, 0.f, 0.f, 0.f};

  for (int k = 0; k < IDIM; k += 64) {
    __syncthreads();
#pragma unroll
    for (int sh = 0; sh < 4; sh++) {
      load_lds16(ap[sh], la + sh * 4096);
      load_lds16(bp[sh], lb + sh * 4096);
      ap[sh] += 64;
      bp[sh] += 64;
    }
    __syncthreads();
#pragma unroll
    for (int kh = 0; kh < 2; kh++) {
      bf16x8 af[4], bfr[4];
#pragma unroll
      for (int i = 0; i < 4; i++) {
        const int ra = wm + i * 16 + l16;
        af[i] = *(const bf16x8*)((const char*)sA + ra * 128 +
                                 ((kh * 4 + quad) ^ (ra & 7)) * 16);
        const int rb = wn + i * 16 + l16;
        bfr[i] = *(const bf16x8*)((const char*)sB + rb * 128 +
                                  ((kh * 4 + quad) ^ (rb & 7)) * 16);
      }
#pragma unroll
      for (int im = 0; im < 4; im++)
#pragma unroll
        for (int in = 0; in < 4; in++)
          acc[im][in] = mfma_bf16(af[im], bfr[in], acc[im][in]);
    }
  }

#pragma unroll
  for (int im = 0; im < 4; im++) {
#pragma unroll
    for (int r = 0; r < 4; r++) {
      const int t = m0 + wm + im * 16 + quad * 4 + r;
      const int v1 = inv[2 * t], v2 = inv[2 * t + 1];
      const size_t r1 = base[v1 >> 14] + (v1 & (T_TOTAL - 1));
      const size_t r2 = base[v2 >> 14] + (v2 & (T_TOTAL - 1));
      const bf16x4 y1 = yb4[(r1 * 16 + nseg) * 16 + l16];
      const bf16x4 y2 = yb4[(r2 * 16 + nseg) * 16 + l16];
      float* op = out + (size_t)t * HDIM + n0 + wn + l16;
#pragma unroll
      for (int in = 0; in < 4; in++)
        op[in * 16] = acc[im][in][r] + (float)y1[in] + (float)y2[in];
    }
  }
}

// ---------------------------------------------------------------------------
// Fallback path (ws too small for yb): shared GEMM plain stores, then routed
// atomic scatter-add on packed inter.
// ---------------------------------------------------------------------------
__global__ __launch_bounds__(256, 2) void k_down_s(const __bf16* __restrict__ iA,
                                                   const __bf16* __restrict__ wB,
                                                   float* __restrict__ out) {
  __shared__ __bf16 sA[128][64];
  __shared__ __bf16 sB[128][64];
  const int tid = threadIdx.x, w = tid >> 6, lane = tid & 63;
  const int m0 = blockIdx.x * 128, n0 = blockIdx.y * 128;
  const int quad = lane >> 4, l16 = lane & 15;
  const int wm = (w & 1) * 64, wn = (w >> 1) * 64;

  const int sr = tid >> 3;
  const int scs = ((tid & 7) ^ (sr & 7)) * 8;
  const __bf16* ap[4];
  const __bf16* bp[4];
#pragma unroll
  for (int sh = 0; sh < 4; sh++) {
    ap[sh] = iA + (size_t)(m0 + sh * 32 + sr) * IDIM + scs;
    bp[sh] = wB + (size_t)(n0 + sh * 32 + sr) * IDIM + scs;
  }
  char* const la = (char*)sA + w * 1024;
  char* const lb = (char*)sB + w * 1024;

  f32x4 acc[4][4];
#pragma unroll
  for (int im = 0; im < 4; im++)
#pragma unroll
    for (int in = 0; in < 4; in++) acc[im][in] = {0.f, 0.f, 0.f, 0.f};

  for (int k = 0; k < IDIM; k += 64) {
    __syncthreads();
#pragma unroll
    for (int sh = 0; sh < 4; sh++) {
      load_lds16(ap[sh], la + sh * 4096);
      load_lds16(bp[sh], lb + sh * 4096);
      ap[sh] += 64;
      bp[sh] += 64;
    }
    __syncthreads();
#pragma unroll
    for (int kh = 0; kh < 2; kh++) {
      bf16x8 af[4], bfr[4];
#pragma unroll
      for (int i = 0; i < 4; i++) {
        const int ra = wm + i * 16 + l16;
        af[i] = *(const bf16x8*)((const char*)sA + ra * 128 +
                                 ((kh * 4 + quad) ^ (ra & 7)) * 16);
        const int rb = wn + i * 16 + l16;
        bfr[i] = *(const bf16x8*)((const char*)sB + rb * 128 +
                                  ((kh * 4 + quad) ^ (rb & 7)) * 16);
      }
#pragma unroll
      for (int im = 0; im < 4; im++)
#pragma unroll
        for (int in = 0; in < 4; in++)
          acc[im][in] = mfma_bf16(af[im], bfr[in], acc[im][in]);
    }
  }

#pragma unroll
  for (int im = 0; im < 4; im++) {
#pragma unroll
    for (int r = 0; r < 4; r++) {
      const int t = m0 + wm + im * 16 + quad * 4 + r;
#pragma unroll
      for (int in = 0; in < 4; in++)
        out[(size_t)t * HDIM + n0 + wn + in * 16 + l16] = acc[im][in][r];
    }
  }
}

__global__ __launch_bounds__(256, 2) void k_down_r(
    const __bf16* __restrict__ inter, const __bf16* __restrict__ WdT,
    const int* __restrict__ tok, const int* __restrict__ cnt,
    const int* __restrict__ base, float* __restrict__ out) {
  const int e = blockIdx.z;
  const int cnt_e = cnt[e * CNT_STRIDE];
  const int m0 = blockIdx.x * 128;
  if (m0 >= cnt_e) return;
  const int rowb = base[e];

  __shared__ __bf16 sA[128][64];
  __shared__ __bf16 sB[128][64];
  const int tid = threadIdx.x, w = tid >> 6, lane = tid & 63;
  const int n0 = blockIdx.y * 128;
  const int quad = lane >> 4, l16 = lane & 15;
  const int wm = (w & 1) * 64, wn = (w >> 1) * 64;

  const int sr = tid >> 3;
  const int scs = ((tid & 7) ^ (sr & 7)) * 8;
  const __bf16* ap[4];
  const __bf16* bp[4];
#pragma unroll
  for (int sh = 0; sh < 4; sh++) {
    int s = m0 + sh * 32 + sr;
    if (s > cnt_e - 1) s = cnt_e - 1;
    ap[sh] = inter + (size_t)(rowb + s) * IDIM + scs;
    bp[sh] = WdT + ((size_t)e * HDIM + n0 + sh * 32 + sr) * IDIM + scs;
  }
  char* const la = (char*)sA + w * 1024;
  char* const lb = (char*)sB + w * 1024;

  f32x4 acc[4][4];
#pragma unroll
  for (int im = 0; im < 4; im++)
#pragma unroll
    for (int in = 0; in < 4; in++) acc[im][in] = {0.f, 0.f, 0.f, 0.f};

  for (int k = 0; k < IDIM; k += 64) {
    __syncthreads();
#pragma unroll
    for (int sh = 0; sh < 4; sh++) {
      load_lds16(ap[sh], la + sh * 4096);
      load_lds16(bp[sh], lb + sh * 4096);
      ap[sh] += 64;
      bp[sh] += 64;
    }
    __syncthreads();
#pragma unroll
    for (int kh = 0; kh < 2; kh++) {
      bf16x8 af[4], bfr[4];
#pragma unroll
      for (int i = 0; i < 4; i++) {
        const int ra = wm + i * 16 + l16;
        af[i] = *(const bf16x8*)((const char*)sA + ra * 128 +
                                 ((kh * 4 + quad) ^ (ra & 7)) * 16);
        const int rb = wn + i * 16 + l16;
        bfr[i] = *(const bf16x8*)((const char*)sB + rb * 128 +
                                  ((kh * 4 + quad) ^ (rb & 7)) * 16);
      }
#pragma unroll
      for (int im = 0; im < 4; im++)
#pragma unroll
        for (int in = 0; in < 4; in++)
          acc[im][in] = mfma_bf16(af[im], bfr[in], acc[im][in]);
    }
  }

#pragma unroll
  for (int im = 0; im < 4; im++) {
#pragma unroll
    for (int r = 0; r < 4; r++) {
      const int slot = m0 + wm + im * 16 + quad * 4 + r;
      if (slot < cnt_e) {
        const int t = tok[e * T_TOTAL + slot];
#pragma unroll
        for (int in = 0; in < 4; in++)
          atomicAdd(&out[(size_t)t * HDIM + n0 + wn + in * 16 + l16],
                    acc[im][in][r]);
      }
    }
  }
}

// ---------------------------------------------------------------------------
extern "C" void kernel_launch(void* const* d_in, const int* in_sizes, int n_in,
                              void* d_out, int out_size, void* d_ws,
                              size_t ws_size, hipStream_t stream) {
  const float* x = (const float*)d_in[0];
  const float* gw = (const float*)d_in[1];
  const float* Wg = (const float*)d_in[2];
  const float* Wu = (const float*)d_in[3];
  const float* Wd = (const float*)d_in[4];
  const float* sWg = (const float*)d_in[5];
  const float* sWu = (const float*)d_in[6];
  const float* sWd = (const float*)d_in[7];
  float* out = (float*)d_out;

  char* ws = (char*)d_ws;
  size_t off = 0;
  auto alloc = [&](size_t n) {
    char* p = ws + off;
    off += (n + 255) & ~(size_t)255;
    return p;
  };
  // --- persistent through phase B ---
  __bf16* WdT = (__bf16*)alloc((size_t)NE * HDIM * IDIM * 2);       // 9.4 MB
  int* tok = (int*)alloc((size_t)8 * T_TOTAL * 4);                  // 512 KB
  float* wtl = (float*)alloc((size_t)8 * T_TOTAL * 4);              // 512 KB
  int* cnt = (int*)alloc(8 * CNT_STRIDE * 4);
  int* inv = (int*)alloc((size_t)T_TOTAL * 2 * 4);                  // 128 KB
  int* base = (int*)alloc(16 * 4);
  __bf16* inter = (__bf16*)alloc((size_t)(3 * T_TOTAL) * IDIM * 2); // 50.3 MB
  const size_t off_persist = off;                                   // ~60.9 MB
  // --- dead after k_gu (yb aliases this region) ---
  __bf16* xb = (__bf16*)alloc((size_t)T_TOTAL * HDIM * 2);          // 33.5 MB
  __bf16* Wfu = (__bf16*)alloc((size_t)NE * 1024 * HDIM * 2);       // 18.9 MB

  // Frag-packed routed down-proj output: 2T rows x H bf16 = 67 MB, aliased
  // over xb+Wfu (stream order: k_down_rs runs after k_gu's last read).
  const size_t yb_bytes = (size_t)2 * T_TOTAL * HDIM * 2;
  const bool store_path = (off_persist + yb_bytes) <= ws_size;  // needs 128 MB
  bf16x4* yb4 = (bf16x4*)(ws + off_persist);

  hipMemsetAsync(cnt, 0, 8 * CNT_STRIDE * 4, stream);

  k_gate<<<dim3(T_TOTAL / 64), dim3(256), 0, stream>>>(x, gw, xb, tok, wtl,
                                                       cnt, inv);
  // All weight prep (G-fuse, U-fuse, Wd transpose) + scan in one launch.
  k_wprep<<<dim3(16, 16, 27), dim3(256), 0, stream>>>(Wg, Wu, Wd, sWg, sWu,
                                                      sWd, Wfu, WdT, cnt, base);

  // Phase A: fused GU into packed inter; N-fastest grid (kept).
  k_gu<<<dim3(1024 / 128, T_TOTAL / 128, NE), dim3(256), 0, stream>>>(
      xb, Wfu, tok, wtl, cnt, base, inter);

  if (store_path) {
    // routed experts -> frag-packed bf16 yb4 (sequential stores), then
    // shared + inv-gathered combine. M-fastest grid.
    k_down_rs<<<dim3(T_TOTAL / 128, HDIM / 128, 8), dim3(256), 0, stream>>>(
        inter, WdT, cnt, base, yb4);
    k_down_sc<<<dim3(T_TOTAL / 128, HDIM / 128), dim3(256), 0, stream>>>(
        inter + (size_t)SH_BASE * IDIM, WdT + (size_t)8 * HDIM * IDIM, yb4, inv,
        base, out);
  } else {
    // fallback: shared GEMM stores, routed atomic scatter-add
    k_down_s<<<dim3(T_TOTAL / 128, HDIM / 128), dim3(256), 0, stream>>>(
        inter + (size_t)SH_BASE * IDIM, WdT + (size_t)8 * HDIM * IDIM, out);
    k_down_r<<<dim3(T_TOTAL / 128, HDIM / 128, 8), dim3(256), 0, stream>>>(
        inter, WdT, tok, cnt, base, out);
  }
}

// Round 12
// 405.058 us; speedup vs baseline: 1.1109x; 1.0351x over previous
//
#include <hip/hip_runtime.h>
#include <hip/hip_bf16.h>
#include <math.h>

// ---------------------------------------------------------------------------
// DeepseekV2 MoE: T=16384 tokens, H=1024, E=8 routed (top-2) + 1 shared, I=512
// Round 16: k_gate TLP (single variable vs r15).
//  - k_gate: 64 tokens/block x 256 blocks (1 blk/CU, 16 serial iters) ->
//    32 tokens/block x 512 blocks (2 blk/CU, 8 iters). Latency-bound kernel
//    (~25us vs ~16us BW floor) gains TLP; algorithm/semantics unchanged.
//  - r15 confirmed: bf16 yb4 (absmax unchanged 0.03125, non-gu -21us). r15's
//    k_gu "regression" 135.6->154.4 was cross-run clock variance (FETCH
//    identical, hbm_gbps -15%, within-run spread <1%).
//  - Everything else frozen: merged N-fastest k_gu, M-fastest rs/sc, bf16
//    frag-packed yb, wprep+scan fusion, 5 launches, atomic fallback.
// ---------------------------------------------------------------------------

#define T_TOTAL 16384
#define HDIM 1024
#define IDIM 512
#define NE 9  // 8 routed + 1 shared (expert index 8)
#define CNT_STRIDE 16
#define SH_BASE 32768  // packed-inter row where shared expert starts

typedef __bf16 bf16x8 __attribute__((ext_vector_type(8)));
typedef __bf16 bf16x4 __attribute__((ext_vector_type(4)));
typedef float f32x4 __attribute__((ext_vector_type(4)));

typedef __attribute__((address_space(1))) void gvoid_t;
typedef __attribute__((address_space(3))) void lvoid_t;

__device__ __forceinline__ void load_lds16(const void* g, void* l) {
  // 16B/lane; LDS dest = wave-uniform base + lane*16 (global src may scatter)
  __builtin_amdgcn_global_load_lds((const gvoid_t*)g, (lvoid_t*)l, 16, 0, 0);
}

__device__ __forceinline__ f32x4 mfma_bf16(bf16x8 a, bf16x8 b, f32x4 c) {
  return __builtin_amdgcn_mfma_f32_16x16x32_bf16(a, b, c, 0, 0, 0);
}

// ---------------------------------------------------------------------------
// Gate: block-aggregated slot assignment; 32 tokens/block, 8 iters/wave.
// Writes inv[t*2+j] = e*16384+slot (T_TOTAL = 2^14).
// ---------------------------------------------------------------------------
__global__ __launch_bounds__(256) void k_gate(const float* __restrict__ x,
                                              const float* __restrict__ gw,
                                              __bf16* __restrict__ xb,
                                              int* __restrict__ tok,
                                              float* __restrict__ wtl,
                                              int* __restrict__ cnt,
                                              int* __restrict__ inv) {
  __shared__ int s_eid[32][2];
  __shared__ float s_wt[32][2];
  __shared__ int s_rank[32][2];
  __shared__ int lcnt[8];
  __shared__ int lbase[8];
  const int wv = threadIdx.x >> 6, lane = threadIdx.x & 63;
  if (threadIdx.x < 8) lcnt[threadIdx.x] = 0;
  __syncthreads();

  for (int i = 0; i < 8; i++) {
    const int tl = wv * 8 + i;
    const int t = blockIdx.x * 32 + tl;
    const float* xr = x + (size_t)t * HDIM + lane * 16;
    float4 xv[4];
#pragma unroll
    for (int j = 0; j < 4; j++) xv[j] = ((const float4*)xr)[j];

    bf16x8 v0, v1;
#pragma unroll
    for (int j = 0; j < 8; j++) v0[j] = (__bf16)((const float*)xv)[j];
#pragma unroll
    for (int j = 0; j < 8; j++) v1[j] = (__bf16)((const float*)xv)[j + 8];
    bf16x8* xbo = (bf16x8*)(xb + (size_t)t * HDIM + lane * 16);
    xbo[0] = v0;
    xbo[1] = v1;

    float acc[8];
#pragma unroll
    for (int e = 0; e < 8; e++) {
      const float4* gp = (const float4*)(gw + e * HDIM + lane * 16);
      float s = 0.f;
#pragma unroll
      for (int j = 0; j < 4; j++) {
        float4 g = gp[j];
        s += xv[j].x * g.x + xv[j].y * g.y + xv[j].z * g.z + xv[j].w * g.w;
      }
      acc[e] = s;
    }
#pragma unroll
    for (int d = 32; d >= 1; d >>= 1) {
#pragma unroll
      for (int e = 0; e < 8; e++) acc[e] += __shfl_xor(acc[e], d, 64);
    }
    if (lane == 0) {
      float mx = acc[0];
#pragma unroll
      for (int e = 1; e < 8; e++) mx = fmaxf(mx, acc[e]);
      float p[8], Z = 0.f;
#pragma unroll
      for (int e = 0; e < 8; e++) {
        p[e] = expf(acc[e] - mx);
        Z += p[e];
      }
#pragma unroll
      for (int e = 0; e < 8; e++) p[e] /= Z;
      int i1 = 0;
#pragma unroll
      for (int e = 1; e < 8; e++)
        if (p[e] > p[i1]) i1 = e;
      int i2 = (i1 == 0) ? 1 : 0;
#pragma unroll
      for (int e = 0; e < 8; e++)
        if (e != i1 && p[e] > p[i2]) i2 = e;
      const float s12 = p[i1] + p[i2] + 1e-20f;
      s_eid[tl][0] = i1;
      s_eid[tl][1] = i2;
      s_wt[tl][0] = p[i1] / s12;
      s_wt[tl][1] = p[i2] / s12;
    }
  }
  __syncthreads();

  if (threadIdx.x < 32) {
    s_rank[threadIdx.x][0] = atomicAdd(&lcnt[s_eid[threadIdx.x][0]], 1);
    s_rank[threadIdx.x][1] = atomicAdd(&lcnt[s_eid[threadIdx.x][1]], 1);
  }
  __syncthreads();
  if (threadIdx.x < 8)
    lbase[threadIdx.x] =
        atomicAdd(&cnt[threadIdx.x * CNT_STRIDE], lcnt[threadIdx.x]);
  __syncthreads();
  if (threadIdx.x < 32) {
    const int t = blockIdx.x * 32 + threadIdx.x;
#pragma unroll
    for (int j = 0; j < 2; j++) {
      const int e = s_eid[threadIdx.x][j];
      const int slot = lbase[e] + s_rank[threadIdx.x][j];
      tok[e * T_TOTAL + slot] = t;
      wtl[e * T_TOTAL + slot] = s_wt[threadIdx.x][j];
      inv[t * 2 + j] = e * T_TOTAL + slot;
    }
  }
}

// ---------------------------------------------------------------------------
// Fused weight prep, single launch. z in [0,9): Wg->Wfu(+0); z in [9,18):
// Wu->Wfu(+16); z in [18,27): Wd->WdT. Scan(cnt)->base folded into block
// (0,0,26) thread 0 (stream-ordered after k_gate).
// ---------------------------------------------------------------------------
__global__ __launch_bounds__(256) void k_wprep(
    const float* __restrict__ Wg, const float* __restrict__ Wu,
    const float* __restrict__ Wd, const float* __restrict__ sWg,
    const float* __restrict__ sWu, const float* __restrict__ sWd,
    __bf16* __restrict__ Wfu, __bf16* __restrict__ WdT,
    const int* __restrict__ cnt, int* __restrict__ base) {
  if (blockIdx.z == 26 && blockIdx.x == 0 && blockIdx.y == 0 &&
      threadIdx.x == 0) {
    int s = 0;
#pragma unroll
    for (int e = 0; e < 8; e++) {
      base[e] = s;
      s += cnt[e * CNT_STRIDE];
    }
  }

  __shared__ float tile[64][65];
  const int z = blockIdx.z;
  const int t = threadIdx.x;

  if (z < 18) {
    // fused-GU transpose: src fp32 [1024 h][512 i] -> Wfu [1024 f][1024 h]
    if (blockIdx.x >= IDIM / 64) return;
    const int b = (z < 9) ? z : z - 9;
    const int u16off = (z < 9) ? 0 : 16;
    const float* w8 = (z < 9) ? Wg : Wu;
    const float* w1 = (z < 9) ? sWg : sWu;
    const float* src = (b < 8) ? (w8 + (size_t)b * HDIM * IDIM) : w1;
    const int c0 = blockIdx.x * 64, r0 = blockIdx.y * 64;  // c=i, r=h

#pragma unroll
    for (int j = 0; j < 4; j++) {
      const int rr = (t >> 4) + j * 16;
      const int cc = (t & 15) * 4;
      const float4 v =
          *(const float4*)(src + (size_t)(r0 + rr) * IDIM + c0 + cc);
      tile[rr][cc] = v.x;
      tile[rr][cc + 1] = v.y;
      tile[rr][cc + 2] = v.z;
      tile[rr][cc + 3] = v.w;
    }
    __syncthreads();

#pragma unroll
    for (int j = 0; j < 2; j++) {
      const int cidx = (t >> 3) + j * 32;  // i-local
      const int rseg = (t & 7) * 8;        // h-local start
      const int ic = c0 + cidx;
      const int f = 2 * (ic & ~15) + (ic & 15) + u16off;
      bf16x8 v;
#pragma unroll
      for (int k = 0; k < 8; k++) v[k] = (__bf16)tile[rseg + k][cidx];
      *(bf16x8*)(Wfu + (size_t)b * 1024 * HDIM + (size_t)f * HDIM + r0 + rseg) =
          v;
    }
  } else {
    // Wd transpose: src fp32 [512 i][1024 h] -> WdT [1024 h][512 i]
    if (blockIdx.y >= IDIM / 64) return;
    const int b = z - 18;
    const float* src = (b < 8) ? (Wd + (size_t)b * IDIM * HDIM) : sWd;
    const int c0 = blockIdx.x * 64, r0 = blockIdx.y * 64;  // c=h, r=i

#pragma unroll
    for (int j = 0; j < 4; j++) {
      const int rr = (t >> 4) + j * 16;
      const int cc = (t & 15) * 4;
      const float4 v =
          *(const float4*)(src + (size_t)(r0 + rr) * HDIM + c0 + cc);
      tile[rr][cc] = v.x;
      tile[rr][cc + 1] = v.y;
      tile[rr][cc + 2] = v.z;
      tile[rr][cc + 3] = v.w;
    }
    __syncthreads();

#pragma unroll
    for (int j = 0; j < 2; j++) {
      const int cidx = (t >> 3) + j * 32;  // h-local
      const int rseg = (t & 7) * 8;        // i-local start
      bf16x8 v;
#pragma unroll
      for (int k = 0; k < 8; k++) v[k] = (__bf16)tile[rseg + k][cidx];
      *(bf16x8*)(WdT + (size_t)b * HDIM * IDIM + (size_t)(c0 + cidx) * IDIM +
                 r0 + rseg) = v;
    }
  }
}

// ---------------------------------------------------------------------------
// Phase A: one GEMM [slots x 128 fused cols], K=H, all 9 experts, one launch.
// N-FASTEST grid (A/B-confirmed -7us). Output rows PACKED.
// acc[im][2p]=G, acc[im][2p+1]=U for i-col = (n0+wn)/2 + p*16 + l16.
// ---------------------------------------------------------------------------
__global__ __launch_bounds__(256, 2) void k_gu(
    const __bf16* __restrict__ xb, const __bf16* __restrict__ Wfu,
    const int* __restrict__ tok, const float* __restrict__ wtl,
    const int* __restrict__ cnt, const int* __restrict__ base,
    __bf16* __restrict__ inter) {
  const int e = blockIdx.z;
  const bool se = (e == 8);
  const int cnt_e = se ? T_TOTAL : cnt[e * CNT_STRIDE];
  const int m0 = blockIdx.y * 128;
  if (m0 >= cnt_e) return;  // uniform early-exit before any barrier
  const int rowb = se ? SH_BASE : base[e];

  __shared__ __bf16 sA[128][64];
  __shared__ __bf16 sB[128][64];
  const int tid = threadIdx.x, w = tid >> 6, lane = tid & 63;
  const int n0 = blockIdx.x * 128;  // fused-row base (0..896)
  const int quad = lane >> 4, l16 = lane & 15;
  const int wm = (w & 1) * 64, wn = (w >> 1) * 64;

  // staging: 256 thr x 16B = 4KB/shot = 32 rows of 128B; 4 shots per buffer
  const int sr = tid >> 3;                     // row within shot
  const int scs = ((tid & 7) ^ (sr & 7)) * 8;  // swizzled source offset (elems)
  const __bf16* ap[4];
  const __bf16* bp[4];
#pragma unroll
  for (int sh = 0; sh < 4; sh++) {
    int s = m0 + sh * 32 + sr;
    if (s > cnt_e - 1) s = cnt_e - 1;
    const int t = se ? s : tok[e * T_TOTAL + s];
    ap[sh] = xb + (size_t)t * HDIM + scs;
    bp[sh] = Wfu + ((size_t)e * 1024 + n0 + sh * 32 + sr) * HDIM + scs;
  }
  char* const la = (char*)sA + w * 1024;  // +lane*16 implicit in global_load_lds
  char* const lb = (char*)sB + w * 1024;

  f32x4 acc[4][4];
#pragma unroll
  for (int im = 0; im < 4; im++)
#pragma unroll
    for (int in = 0; in < 4; in++) acc[im][in] = {0.f, 0.f, 0.f, 0.f};

  for (int k = 0; k < HDIM; k += 64) {
    __syncthreads();
#pragma unroll
    for (int sh = 0; sh < 4; sh++) {
      load_lds16(ap[sh], la + sh * 4096);
      load_lds16(bp[sh], lb + sh * 4096);
      ap[sh] += 64;
      bp[sh] += 64;
    }
    __syncthreads();
#pragma unroll
    for (int kh = 0; kh < 2; kh++) {
      bf16x8 af[4], bfr[4];
#pragma unroll
      for (int i = 0; i < 4; i++) {
        const int ra = wm + i * 16 + l16;
        af[i] = *(const bf16x8*)((const char*)sA + ra * 128 +
                                 ((kh * 4 + quad) ^ (ra & 7)) * 16);
        const int rb = wn + i * 16 + l16;
        bfr[i] = *(const bf16x8*)((const char*)sB + rb * 128 +
                                  ((kh * 4 + quad) ^ (rb & 7)) * 16);
      }
#pragma unroll
      for (int im = 0; im < 4; im++)
#pragma unroll
        for (int in = 0; in < 4; in++)
          acc[im][in] = mfma_bf16(af[im], bfr[in], acc[im][in]);
    }
  }

  // epilogue: C/D col=lane&15, row=quad*4+r; G/U pairs in even/odd n-frags
#pragma unroll
  for (int im = 0; im < 4; im++) {
#pragma unroll
    for (int r = 0; r < 4; r++) {
      const int slot = m0 + wm + im * 16 + quad * 4 + r;
      if (slot < cnt_e) {
        const float wt = se ? 1.0f : wtl[e * T_TOTAL + slot];
        __bf16* op =
            inter + ((size_t)(rowb + slot)) * IDIM + ((n0 + wn) >> 1) + l16;
#pragma unroll
        for (int p = 0; p < 2; p++) {
          const float g = acc[im][2 * p][r];
          const float u = acc[im][2 * p + 1][r];
          const float v =
              wt * u * 0.5f * g * (1.0f + erff(g * 0.70710678118654752f));
          op[p * 16] = (__bf16)v;
        }
      }
    }
  }
}

// ---------------------------------------------------------------------------
// Phase B routed: per expert e, gathered GEMM over packed inter rows @ Wd[e]
// -> frag-packed BF16x4 rows of yb, SEQUENTIAL stores at row=base[e]+slot:
// yb4[(row*16 + nseg)*16 + l16] = cols {nseg*64 + in*16 + l16}. M-FASTEST grid.
// ---------------------------------------------------------------------------
__global__ __launch_bounds__(256, 2) void k_down_rs(
    const __bf16* __restrict__ inter, const __bf16* __restrict__ WdT,
    const int* __restrict__ cnt, const int* __restrict__ base,
    bf16x4* __restrict__ yb4) {
  const int e = blockIdx.z;
  const int cnt_e = cnt[e * CNT_STRIDE];
  const int m0 = blockIdx.x * 128;
  if (m0 >= cnt_e) return;
  const int rowb = base[e];

  __shared__ __bf16 sA[128][64];
  __shared__ __bf16 sB[128][64];
  const int tid = threadIdx.x, w = tid >> 6, lane = tid & 63;
  const int n0 = blockIdx.y * 128;
  const int quad = lane >> 4, l16 = lane & 15;
  const int wm = (w & 1) * 64, wn = (w >> 1) * 64;
  const int nseg = (n0 + wn) >> 6;

  const int sr = tid >> 3;
  const int scs = ((tid & 7) ^ (sr & 7)) * 8;
  const __bf16* ap[4];
  const __bf16* bp[4];
#pragma unroll
  for (int sh = 0; sh < 4; sh++) {
    int s = m0 + sh * 32 + sr;
    if (s > cnt_e - 1) s = cnt_e - 1;
    ap[sh] = inter + (size_t)(rowb + s) * IDIM + scs;
    bp[sh] = WdT + ((size_t)e * HDIM + n0 + sh * 32 + sr) * IDIM + scs;
  }
  char* const la = (char*)sA + w * 1024;
  char* const lb = (char*)sB + w * 1024;

  f32x4 acc[4][4];
#pragma unroll
  for (int im = 0; im < 4; im++)
#pragma unroll
    for (int in = 0; in < 4; in++) acc[im][in] = {0.f, 0.f, 0.f, 0.f};

  for (int k = 0; k < IDIM; k += 64) {
    __syncthreads();
#pragma unroll
    for (int sh = 0; sh < 4; sh++) {
      load_lds16(ap[sh], la + sh * 4096);
      load_lds16(bp[sh], lb + sh * 4096);
      ap[sh] += 64;
      bp[sh] += 64;
    }
    __syncthreads();
#pragma unroll
    for (int kh = 0; kh < 2; kh++) {
      bf16x8 af[4], bfr[4];
#pragma unroll
      for (int i = 0; i < 4; i++) {
        const int ra = wm + i * 16 + l16;
        af[i] = *(const bf16x8*)((const char*)sA + ra * 128 +
                                 ((kh * 4 + quad) ^ (ra & 7)) * 16);
        const int rb = wn + i * 16 + l16;
        bfr[i] = *(const bf16x8*)((const char*)sB + rb * 128 +
                                  ((kh * 4 + quad) ^ (rb & 7)) * 16);
      }
#pragma unroll
      for (int im = 0; im < 4; im++)
#pragma unroll
        for (int in = 0; in < 4; in++)
          acc[im][in] = mfma_bf16(af[im], bfr[in], acc[im][in]);
    }
  }

#pragma unroll
  for (int im = 0; im < 4; im++) {
#pragma unroll
    for (int r = 0; r < 4; r++) {
      const int slot = m0 + wm + im * 16 + quad * 4 + r;
      if (slot < cnt_e) {
        const size_t row = (size_t)(rowb + slot);
        bf16x4 v;
#pragma unroll
        for (int in = 0; in < 4; in++) v[in] = (__bf16)acc[im][in][r];
        yb4[(row * 16 + nseg) * 16 + l16] = v;
      }
    }
  }
}

// ---------------------------------------------------------------------------
// Phase B shared + combine: out[t] = inter[shared] @ sWd + yb[r1(t)] + yb[r2(t)].
// Routed rows gathered from frag-packed bf16 yb4 via inv[]; fp32 final sum.
// M-FASTEST grid.
// ---------------------------------------------------------------------------
__global__ __launch_bounds__(256, 2) void k_down_sc(
    const __bf16* __restrict__ iA, const __bf16* __restrict__ wB,
    const bf16x4* __restrict__ yb4, const int* __restrict__ inv,
    const int* __restrict__ base, float* __restrict__ out) {
  __shared__ __bf16 sA[128][64];
  __shared__ __bf16 sB[128][64];
  const int tid = threadIdx.x, w = tid >> 6, lane = tid & 63;
  const int m0 = blockIdx.x * 128, n0 = blockIdx.y * 128;
  const int quad = lane >> 4, l16 = lane & 15;
  const int wm = (w & 1) * 64, wn = (w >> 1) * 64;
  const int nseg = (n0 + wn) >> 6;

  const int sr = tid >> 3;
  const int scs = ((tid & 7) ^ (sr & 7)) * 8;
  const __bf16* ap[4];
  const __bf16* bp[4];
#pragma unroll
  for (int sh = 0; sh < 4; sh++) {
    ap[sh] = iA + (size_t)(m0 + sh * 32 + sr) * IDIM + scs;
    bp[sh] = wB + (size_t)(n0 + sh * 32 + sr) * IDIM + scs;
  }
  char* const la = (char*)sA + w * 1024;
  char* const lb = (char*)sB + w * 1024;

  f32x4 acc[4][4];
#pragma unroll
  for (int im = 0; im < 4; im++)
#pragma unroll
    for (int in = 0; in < 4; in++) acc[im][in] = {0.f, 0.f, 0.f, 0.f};

  for (int k = 0; k < IDIM; k += 64) {
    __syncthreads();
#pragma unroll
    for (int sh = 0; sh < 4; sh++) {
      load_lds16(ap[sh], la + sh * 4096);
      load_lds16(bp[sh], lb + sh * 4096);
      ap[sh] += 64;
      bp[sh] += 64;
    }
    __syncthreads();
#pragma unroll
    for (int kh = 0; kh < 2; kh++) {
      bf16x8 af[4], bfr[4];
#pragma unroll
      for (int i = 0; i < 4; i++) {
        const int ra = wm + i * 16 + l16;
        af[i] = *(const bf16x8*)((const char*)sA + ra * 128 +
                                 ((kh * 4 + quad) ^ (ra & 7)) * 16);
        const int rb = wn + i * 16 + l16;
        bfr[i] = *(const bf16x8*)((const char*)sB + rb * 128 +
                                  ((kh * 4 + quad) ^ (rb & 7)) * 16);
      }
#pragma unroll
      for (int im = 0; im < 4; im++)
#pragma unroll
        for (int in = 0; in < 4; in++)
          acc[im][in] = mfma_bf16(af[im], bfr[in], acc[im][in]);
    }
  }

#pragma unroll
  for (int im = 0; im < 4; im++) {
#pragma unroll
    for (int r = 0; r < 4; r++) {
      const int t = m0 + wm + im * 16 + quad * 4 + r;
      const int v1 = inv[2 * t], v2 = inv[2 * t + 1];
      const size_t r1 = base[v1 >> 14] + (v1 & (T_TOTAL - 1));
      const size_t r2 = base[v2 >> 14] + (v2 & (T_TOTAL - 1));
      const bf16x4 y1 = yb4[(r1 * 16 + nseg) * 16 + l16];
      const bf16x4 y2 = yb4[(r2 * 16 + nseg) * 16 + l16];
      float* op = out + (size_t)t * HDIM + n0 + wn + l16;
#pragma unroll
      for (int in = 0; in < 4; in++)
        op[in * 16] = acc[im][in][r] + (float)y1[in] + (float)y2[in];
    }
  }
}

// ---------------------------------------------------------------------------
// Fallback path (ws too small for yb): shared GEMM plain stores, then routed
// atomic scatter-add on packed inter.
// ---------------------------------------------------------------------------
__global__ __launch_bounds__(256, 2) void k_down_s(const __bf16* __restrict__ iA,
                                                   const __bf16* __restrict__ wB,
                                                   float* __restrict__ out) {
  __shared__ __bf16 sA[128][64];
  __shared__ __bf16 sB[128][64];
  const int tid = threadIdx.x, w = tid >> 6, lane = tid & 63;
  const int m0 = blockIdx.x * 128, n0 = blockIdx.y * 128;
  const int quad = lane >> 4, l16 = lane & 15;
  const int wm = (w & 1) * 64, wn = (w >> 1) * 64;

  const int sr = tid >> 3;
  const int scs = ((tid & 7) ^ (sr & 7)) * 8;
  const __bf16* ap[4];
  const __bf16* bp[4];
#pragma unroll
  for (int sh = 0; sh < 4; sh++) {
    ap[sh] = iA + (size_t)(m0 + sh * 32 + sr) * IDIM + scs;
    bp[sh] = wB + (size_t)(n0 + sh * 32 + sr) * IDIM + scs;
  }
  char* const la = (char*)sA + w * 1024;
  char* const lb = (char*)sB + w * 1024;

  f32x4 acc[4][4];
#pragma unroll
  for (int im = 0; im < 4; im++)
#pragma unroll
    for (int in = 0; in < 4; in++) acc[im][in] = {0.f, 0.f, 0.f, 0.f};

  for (int k = 0; k < IDIM; k += 64) {
    __syncthreads();
#pragma unroll
    for (int sh = 0; sh < 4; sh++) {
      load_lds16(ap[sh], la + sh * 4096);
      load_lds16(bp[sh], lb + sh * 4096);
      ap[sh] += 64;
      bp[sh] += 64;
    }
    __syncthreads();
#pragma unroll
    for (int kh = 0; kh < 2; kh++) {
      bf16x8 af[4], bfr[4];
#pragma unroll
      for (int i = 0; i < 4; i++) {
        const int ra = wm + i * 16 + l16;
        af[i] = *(const bf16x8*)((const char*)sA + ra * 128 +
                                 ((kh * 4 + quad) ^ (ra & 7)) * 16);
        const int rb = wn + i * 16 + l16;
        bfr[i] = *(const bf16x8*)((const char*)sB + rb * 128 +
                                  ((kh * 4 + quad) ^ (rb & 7)) * 16);
      }
#pragma unroll
      for (int im = 0; im < 4; im++)
#pragma unroll
        for (int in = 0; in < 4; in++)
          acc[im][in] = mfma_bf16(af[im], bfr[in], acc[im][in]);
    }
  }

#pragma unroll
  for (int im = 0; im < 4; im++) {
#pragma unroll
    for (int r = 0; r < 4; r++) {
      const int t = m0 + wm + im * 16 + quad * 4 + r;
#pragma unroll
      for (int in = 0; in < 4; in++)
        out[(size_t)t * HDIM + n0 + wn + in * 16 + l16] = acc[im][in][r];
    }
  }
}

__global__ __launch_bounds__(256, 2) void k_down_r(
    const __bf16* __restrict__ inter, const __bf16* __restrict__ WdT,
    const int* __restrict__ tok, const int* __restrict__ cnt,
    const int* __restrict__ base, float* __restrict__ out) {
  const int e = blockIdx.z;
  const int cnt_e = cnt[e * CNT_STRIDE];
  const int m0 = blockIdx.x * 128;
  if (m0 >= cnt_e) return;
  const int rowb = base[e];

  __shared__ __bf16 sA[128][64];
  __shared__ __bf16 sB[128][64];
  const int tid = threadIdx.x, w = tid >> 6, lane = tid & 63;
  const int n0 = blockIdx.y * 128;
  const int quad = lane >> 4, l16 = lane & 15;
  const int wm = (w & 1) * 64, wn = (w >> 1) * 64;

  const int sr = tid >> 3;
  const int scs = ((tid & 7) ^ (sr & 7)) * 8;
  const __bf16* ap[4];
  const __bf16* bp[4];
#pragma unroll
  for (int sh = 0; sh < 4; sh++) {
    int s = m0 + sh * 32 + sr;
    if (s > cnt_e - 1) s = cnt_e - 1;
    ap[sh] = inter + (size_t)(rowb + s) * IDIM + scs;
    bp[sh] = WdT + ((size_t)e * HDIM + n0 + sh * 32 + sr) * IDIM + scs;
  }
  char* const la = (char*)sA + w * 1024;
  char* const lb = (char*)sB + w * 1024;

  f32x4 acc[4][4];
#pragma unroll
  for (int im = 0; im < 4; im++)
#pragma unroll
    for (int in = 0; in < 4; in++) acc[im][in] = {0.f, 0.f, 0.f, 0.f};

  for (int k = 0; k < IDIM; k += 64) {
    __syncthreads();
#pragma unroll
    for (int sh = 0; sh < 4; sh++) {
      load_lds16(ap[sh], la + sh * 4096);
      load_lds16(bp[sh], lb + sh * 4096);
      ap[sh] += 64;
      bp[sh] += 64;
    }
    __syncthreads();
#pragma unroll
    for (int kh = 0; kh < 2; kh++) {
      bf16x8 af[4], bfr[4];
#pragma unroll
      for (int i = 0; i < 4; i++) {
        const int ra = wm + i * 16 + l16;
        af[i] = *(const bf16x8*)((const char*)sA + ra * 128 +
                                 ((kh * 4 + quad) ^ (ra & 7)) * 16);
        const int rb = wn + i * 16 + l16;
        bfr[i] = *(const bf16x8*)((const char*)sB + rb * 128 +
                                  ((kh * 4 + quad) ^ (rb & 7)) * 16);
      }
#pragma unroll
      for (int im = 0; im < 4; im++)
#pragma unroll
        for (int in = 0; in < 4; in++)
          acc[im][in] = mfma_bf16(af[im], bfr[in], acc[im][in]);
    }
  }

#pragma unroll
  for (int im = 0; im < 4; im++) {
#pragma unroll
    for (int r = 0; r < 4; r++) {
      const int slot = m0 + wm + im * 16 + quad * 4 + r;
      if (slot < cnt_e) {
        const int t = tok[e * T_TOTAL + slot];
#pragma unroll
        for (int in = 0; in < 4; in++)
          atomicAdd(&out[(size_t)t * HDIM + n0 + wn + in * 16 + l16],
                    acc[im][in][r]);
      }
    }
  }
}

// ---------------------------------------------------------------------------
extern "C" void kernel_launch(void* const* d_in, const int* in_sizes, int n_in,
                              void* d_out, int out_size, void* d_ws,
                              size_t ws_size, hipStream_t stream) {
  const float* x = (const float*)d_in[0];
  const float* gw = (const float*)d_in[1];
  const float* Wg = (const float*)d_in[2];
  const float* Wu = (const float*)d_in[3];
  const float* Wd = (const float*)d_in[4];
  const float* sWg = (const float*)d_in[5];
  const float* sWu = (const float*)d_in[6];
  const float* sWd = (const float*)d_in[7];
  float* out = (float*)d_out;

  char* ws = (char*)d_ws;
  size_t off = 0;
  auto alloc = [&](size_t n) {
    char* p = ws + off;
    off += (n + 255) & ~(size_t)255;
    return p;
  };
  // --- persistent through phase B ---
  __bf16* WdT = (__bf16*)alloc((size_t)NE * HDIM * IDIM * 2);       // 9.4 MB
  int* tok = (int*)alloc((size_t)8 * T_TOTAL * 4);                  // 512 KB
  float* wtl = (float*)alloc((size_t)8 * T_TOTAL * 4);              // 512 KB
  int* cnt = (int*)alloc(8 * CNT_STRIDE * 4);
  int* inv = (int*)alloc((size_t)T_TOTAL * 2 * 4);                  // 128 KB
  int* base = (int*)alloc(16 * 4);
  __bf16* inter = (__bf16*)alloc((size_t)(3 * T_TOTAL) * IDIM * 2); // 50.3 MB
  const size_t off_persist = off;                                   // ~60.9 MB
  // --- dead after k_gu (yb aliases this region) ---
  __bf16* xb = (__bf16*)alloc((size_t)T_TOTAL * HDIM * 2);          // 33.5 MB
  __bf16* Wfu = (__bf16*)alloc((size_t)NE * 1024 * HDIM * 2);       // 18.9 MB

  // Frag-packed routed down-proj output: 2T rows x H bf16 = 67 MB, aliased
  // over xb+Wfu (stream order: k_down_rs runs after k_gu's last read).
  const size_t yb_bytes = (size_t)2 * T_TOTAL * HDIM * 2;
  const bool store_path = (off_persist + yb_bytes) <= ws_size;  // needs 128 MB
  bf16x4* yb4 = (bf16x4*)(ws + off_persist);

  hipMemsetAsync(cnt, 0, 8 * CNT_STRIDE * 4, stream);

  k_gate<<<dim3(T_TOTAL / 32), dim3(256), 0, stream>>>(x, gw, xb, tok, wtl,
                                                       cnt, inv);
  // All weight prep (G-fuse, U-fuse, Wd transpose) + scan in one launch.
  k_wprep<<<dim3(16, 16, 27), dim3(256), 0, stream>>>(Wg, Wu, Wd, sWg, sWu,
                                                      sWd, Wfu, WdT, cnt, base);

  // Phase A: fused GU into packed inter; N-fastest grid (kept).
  k_gu<<<dim3(1024 / 128, T_TOTAL / 128, NE), dim3(256), 0, stream>>>(
      xb, Wfu, tok, wtl, cnt, base, inter);

  if (store_path) {
    // routed experts -> frag-packed bf16 yb4 (sequential stores), then
    // shared + inv-gathered combine. M-fastest grid.
    k_down_rs<<<dim3(T_TOTAL / 128, HDIM / 128, 8), dim3(256), 0, stream>>>(
        inter, WdT, cnt, base, yb4);
    k_down_sc<<<dim3(T_TOTAL / 128, HDIM / 128), dim3(256), 0, stream>>>(
        inter + (size_t)SH_BASE * IDIM, WdT + (size_t)8 * HDIM * IDIM, yb4, inv,
        base, out);
  } else {
    // fallback: shared GEMM stores, routed atomic scatter-add
    k_down_s<<<dim3(T_TOTAL / 128, HDIM / 128), dim3(256), 0, stream>>>(
        inter + (size_t)SH_BASE * IDIM, WdT + (size_t)8 * HDIM * IDIM, out);
    k_down_r<<<dim3(T_TOTAL / 128, HDIM / 128, 8), dim3(256), 0, stream>>>(
        inter, WdT, tok, cnt, base, out);
  }
}